// Round 10
// baseline (424.089 us; speedup 1.0000x reference)
//
#include <hip/hip_runtime.h>

namespace {

typedef short s16x8 __attribute__((ext_vector_type(8)));
typedef float f32x4 __attribute__((ext_vector_type(4)));

__device__ __forceinline__ float bf2f(unsigned short u) {
  return __uint_as_float(((unsigned)u) << 16);
}
__device__ __forceinline__ unsigned short f2bf(float f) {
  unsigned u = __float_as_uint(f);
  u += 0x7fffu + ((u >> 16) & 1u);
  return (unsigned short)(u >> 16);
}

// async global->LDS, 16B per lane. LDS dest is wave-uniform base + lane*16.
typedef __attribute__((address_space(3))) unsigned int lds_u32;
typedef __attribute__((address_space(1))) const unsigned int glob_u32;
__device__ __forceinline__ void gl16(const void* g, void* l) {
  __builtin_amdgcn_global_load_lds((glob_u32*)g, (lds_u32*)l, 16, 0, 0);
}

// x (fp32) -> xb (bf16), 35000x512 total; xb lives in d_out (dead until final_mfma3).
__global__ __launch_bounds__(256) void cvt_x3(const float* __restrict__ x0,
                                              const float* __restrict__ x1,
                                              const float* __restrict__ x2,
                                              unsigned short* __restrict__ out) {
  size_t i = ((size_t)blockIdx.x * 256 + threadIdx.x) * 8;
  const float* src;
  size_t off;
  if (i < (size_t)20000 * 512) { src = x0; off = i; }
  else if (i < (size_t)30000 * 512) { src = x1; off = i - (size_t)20000 * 512; }
  else { src = x2; off = i - (size_t)30000 * 512; }
  float4 a = *(const float4*)(src + off);
  float4 b = *(const float4*)(src + off + 4);
  s16x8 v;
  v[0] = (short)f2bf(a.x); v[1] = (short)f2bf(a.y);
  v[2] = (short)f2bf(a.z); v[3] = (short)f2bf(a.w);
  v[4] = (short)f2bf(b.x); v[5] = (short)f2bf(b.y);
  v[6] = (short)f2bf(b.z); v[7] = (short)f2bf(b.w);
  *(s16x8*)(out + i) = v;
}

// fp32 [R][256] -> bf16 [256][R] (transposed). wsh: R=256, wcat: R=512.
struct Tc6 { const float* src[6]; unsigned short* dst[6]; int R[6]; };
__global__ __launch_bounds__(256) void transpose_cvt(Tc6 a) {
  int mat = blockIdx.z;
  int R = a.R[mat];
  int r0 = blockIdx.y * 32, c0 = blockIdx.x * 32;
  if (r0 >= R) return;
  const float* __restrict__ src = a.src[mat];
  unsigned short* __restrict__ dst = a.dst[mat];
  __shared__ float T[32][33];
  int tx = threadIdx.x & 31, ty = threadIdx.x >> 5;
  #pragma unroll
  for (int j = 0; j < 4; ++j) {
    int r = ty + j * 8;
    T[r][tx] = src[(size_t)(r0 + r) * 256 + c0 + tx];
  }
  __syncthreads();
  #pragma unroll
  for (int j = 0; j < 4; ++j) {
    int c = ty + j * 8;
    dst[(size_t)(c0 + c) * R + r0 + tx] = f2bf(T[tx][c]);
  }
}

// Wcbt[256x512] = wshT[256x256](bf16) @ W[512x256]^T(fp32, cvt on load)
struct Comb9 { const unsigned short* A[9]; const float* B[9]; unsigned short* C[9]; };
__global__ __launch_bounds__(256) void combine_mfma(Comb9 g) {
  int z = blockIdx.z;
  const unsigned short* __restrict__ A = g.A[z];
  const float* __restrict__ B = g.B[z];
  unsigned short* __restrict__ C = g.C[z];
  int row0 = blockIdx.y * 128;
  int col0 = blockIdx.x * 128;
  __shared__ unsigned short As[128 * 40];
  __shared__ unsigned short Bs[128 * 40];
  int tid = threadIdx.x, lane = tid & 63, w = tid >> 6;
  int quad = lane >> 4, m16 = lane & 15;
  f32x4 acc[2][8];
  #pragma unroll
  for (int r = 0; r < 2; ++r)
    #pragma unroll
    for (int c = 0; c < 8; ++c) acc[r][c] = (f32x4){0.f, 0.f, 0.f, 0.f};
  for (int k0 = 0; k0 < 256; k0 += 32) {
    #pragma unroll
    for (int i = 0; i < 2; ++i) {
      int ch = tid + i * 256;
      int m = ch >> 2, kk = (ch & 3) * 8;
      *(s16x8*)&As[m * 40 + kk] = *(const s16x8*)(A + (size_t)(row0 + m) * 256 + k0 + kk);
      const float4* bp = (const float4*)(B + (size_t)(col0 + m) * 256 + k0 + kk);
      float4 b0 = bp[0], b1 = bp[1];
      s16x8 bv;
      bv[0] = (short)f2bf(b0.x); bv[1] = (short)f2bf(b0.y);
      bv[2] = (short)f2bf(b0.z); bv[3] = (short)f2bf(b0.w);
      bv[4] = (short)f2bf(b1.x); bv[5] = (short)f2bf(b1.y);
      bv[6] = (short)f2bf(b1.z); bv[7] = (short)f2bf(b1.w);
      *(s16x8*)&Bs[m * 40 + kk] = bv;
    }
    __syncthreads();
    s16x8 af[2], bf[8];
    #pragma unroll
    for (int r = 0; r < 2; ++r)
      af[r] = *(const s16x8*)&As[(w * 32 + r * 16 + m16) * 40 + quad * 8];
    #pragma unroll
    for (int c = 0; c < 8; ++c)
      bf[c] = *(const s16x8*)&Bs[(c * 16 + m16) * 40 + quad * 8];
    #pragma unroll
    for (int r = 0; r < 2; ++r)
      #pragma unroll
      for (int c = 0; c < 8; ++c)
        acc[r][c] = __builtin_amdgcn_mfma_f32_16x16x32_bf16(af[r], bf[c], acc[r][c], 0, 0, 0);
    __syncthreads();
  }
  #pragma unroll
  for (int r = 0; r < 2; ++r)
    #pragma unroll
    for (int i = 0; i < 4; ++i) {
      int row = row0 + w * 32 + r * 16 + quad * 4 + i;
      #pragma unroll
      for (int c = 0; c < 8; ++c)
        C[(size_t)row * 512 + col0 + c * 16 + m16] = f2bf(acc[r][c][i]);
    }
}

// Projections: r7/r9 block shape + bijective XCD swizzle (m204).
// Work id wg = s*942 + y*6 + (combo*2+colhalf): the 6 consecutive wgs of one
// (s,y) row-tile share the same 128x512 A panel. Default dispatch round-robins
// consecutive blocks across the 8 XCD L2s (r9: FETCH 112MB = 3.1x unique A, no
// reuse). The m204 remap gives each XCD a CONTIGUOUS wg chunk, so panel-sharing
// blocks hit one L2 -> panel fetched once.
// SQ_LDS_BANK_CONFLICT (~3.4M) is gl16-write-intrinsic (r7=r9 identical count,
// r8 = exactly 0.75x with 0.75x gl16 ops) -- not a ds_read problem; swizzle kept.
#define PROJ_NWG (6 * 157 * 3)
struct Proj3 { const unsigned short* A[3]; const unsigned short* Bt[3][3];
               unsigned short* C[3][3]; int M[3]; };
__global__ __launch_bounds__(256) void proj_mfma6(Proj3 g) {
  int orig = blockIdx.x;
  const int q = PROJ_NWG / 8, r8v = PROJ_NWG % 8;
  int xcd = orig & 7, idx = orig >> 3;
  int wg = (xcd < r8v ? xcd * (q + 1) : r8v * (q + 1) + (xcd - r8v) * q) + idx;
  int s = wg / 942;
  int rem = wg - s * 942;
  int by = rem / 6;
  int bx = rem - by * 6;
  int M = g.M[s];
  int row0 = by * 128;
  if (row0 >= M) return;
  int combo = bx >> 1;
  int col0 = (bx & 1) * 128;
  const unsigned short* __restrict__ A = g.A[s];
  const unsigned short* __restrict__ Bt = g.Bt[s][combo];   // 256 x 512
  unsigned short* __restrict__ C = g.C[s][combo];           // M x 256
  __shared__ unsigned short As[128 * 32];
  __shared__ unsigned short Bs[128 * 32];
  int tid = threadIdx.x, lane = tid & 63, w = tid >> 6;
  int quad = lane >> 4, m16 = lane & 15;
  int lr = lane >> 2;
  // pre-swizzled global k-chunk (elements)
  int lk = (((lane & 3) ^ (lr & 3) ^ ((lr >> 2) & 3))) * 8;
  int ar0 = row0 + w * 32 + lr;
  int ar1 = ar0 + 16;
  const unsigned short* a0p = A + (size_t)(ar0 < M ? ar0 : M - 1) * 512 + lk;
  const unsigned short* a1p = A + (size_t)(ar1 < M ? ar1 : M - 1) * 512 + lk;
  const unsigned short* b0p = Bt + (size_t)(col0 + w * 32 + lr) * 512 + lk;
  const unsigned short* b1p = b0p + (size_t)16 * 512;
  unsigned short* as0 = &As[w * 1024];
  unsigned short* as1 = &As[w * 1024 + 512];
  unsigned short* bs0 = &Bs[w * 1024];
  unsigned short* bs1 = &Bs[w * 1024 + 512];
  int wr = (w & 1) * 64, wc = (w >> 1) * 64;
  // swizzled read k-chunk (elements)
  int sw = ((quad ^ (m16 & 3) ^ ((m16 >> 2) & 3))) * 8;
  f32x4 acc[4][4];
  #pragma unroll
  for (int r = 0; r < 4; ++r)
    #pragma unroll
    for (int c = 0; c < 4; ++c) acc[r][c] = (f32x4){0.f, 0.f, 0.f, 0.f};
  for (int k0 = 0; k0 < 512; k0 += 32) {
    gl16(a0p + k0, as0);
    gl16(a1p + k0, as1);
    gl16(b0p + k0, bs0);
    gl16(b1p + k0, bs1);
    __syncthreads();
    s16x8 af[4], bf[4];
    #pragma unroll
    for (int r = 0; r < 4; ++r)
      af[r] = *(const s16x8*)&As[(wr + r * 16 + m16) * 32 + sw];
    #pragma unroll
    for (int c = 0; c < 4; ++c)
      bf[c] = *(const s16x8*)&Bs[(wc + c * 16 + m16) * 32 + sw];
    #pragma unroll
    for (int r = 0; r < 4; ++r)
      #pragma unroll
      for (int c = 0; c < 4; ++c)
        acc[r][c] = __builtin_amdgcn_mfma_f32_16x16x32_bf16(af[r], bf[c], acc[r][c], 0, 0, 0);
    __syncthreads();
  }
  #pragma unroll
  for (int r = 0; r < 4; ++r)
    #pragma unroll
    for (int i = 0; i < 4; ++i) {
      int row = row0 + wr + r * 16 + quad * 4 + i;
      if (row < M) {
        #pragma unroll
        for (int c = 0; c < 4; ++c)
          C[(size_t)row * 256 + col0 + wc + c * 16 + m16] = f2bf(acc[r][c][i]);
      }
    }
}

struct Edges6 { const int* src[6]; const int* dst[6]; const float* w[6]; int nE[6]; int cbase[6]; };

// ---- CSR build: LDS-staged two-level counting sort ----
#define BSH 9
#define NB2 137            // ceil(70000 / 512)
#define CAP2 16384         // padded mean ~12.3K; huge margin + overflow path
#define NOV 65536
#define CH 1024
#define NPAY 1120000

__global__ __launch_bounds__(256) void bin1(Edges6 ep,
                                            int* __restrict__ bcur, int* __restrict__ ovcnt,
                                            unsigned long long* __restrict__ rec2,
                                            unsigned long long* __restrict__ ovbuf) {
  int rho = blockIdx.y;
  int nE = ep.nE[rho];
  int chunk = blockIdx.x * CH;
  if (chunk >= nE) return;
  int n = nE - chunk; if (n > CH) n = CH;
  const int* __restrict__ srcp = ep.src[rho];
  const int* __restrict__ dstp = ep.dst[rho];
  const float* __restrict__ wp = ep.w[rho];
  int cb = ep.cbase[rho];
  __shared__ int h[256], excl[256], lcur[256], gbase[256], rsv[256];
  __shared__ int wsum[4];
  __shared__ unsigned long long stage[CH];
  int t = threadIdx.x;
  h[t] = 0;
  gbase[t] = 0;
  __syncthreads();
  int gd[4]; unsigned pv[4];
  #pragma unroll
  for (int j = 0; j < 4; ++j) {
    int idx = t + j * 256;
    gd[j] = -1;
    if (idx < n) {
      int e = chunk + idx;
      int g = cb + dstp[e];
      if (g < 0) g = 0;
      if (g > 69999) g = 69999;       // defensive (inputs guarantee in-range)
      gd[j] = g;
      pv[j] = (((unsigned)f2bf(wp[e])) << 16) | ((unsigned)srcp[e] & 0x7fffu);
      atomicAdd(&h[g >> BSH], 1);
    }
  }
  __syncthreads();
  int hv = h[t];
  int lane = t & 63, wv = t >> 6;
  int v = hv;
  #pragma unroll
  for (int off = 1; off < 64; off <<= 1) {
    int u = __shfl_up(v, off, 64);
    if (lane >= off) v += u;
  }
  if (lane == 63) wsum[wv] = v;
  __syncthreads();
  int add = 0;
  #pragma unroll
  for (int k = 0; k < 3; ++k)
    if (k < wv) add += wsum[k];
  v += add;
  int ex = v - hv;
  excl[t] = ex;
  lcur[t] = ex;
  int rv = 0;
  if (t < NB2 && hv > 0) {
    rv = (hv + 7) & ~7;               // 64B-aligned reservation
    gbase[t] = atomicAdd(&bcur[t], rv);
  }
  rsv[t] = rv;
  __syncthreads();
  #pragma unroll
  for (int j = 0; j < 4; ++j) {
    if (gd[j] >= 0) {
      int b = gd[j] >> BSH;
      int slot = atomicAdd(&lcur[b], 1);
      if (slot >= 0 && slot < CH)
        stage[slot] = ((unsigned long long)(unsigned)gd[j] << 32) | pv[j];
    }
  }
  __syncthreads();
  for (int s = t; s < n; s += 256) {
    int lo = 0, hi = NB2 - 1;
    while (lo < hi) {
      int mid = (lo + hi + 1) >> 1;
      if (excl[mid] <= s) lo = mid; else hi = mid - 1;
    }
    int b = lo;
    int gp = gbase[b] + (s - excl[b]);
    if (gp >= 0 && gp < CAP2) rec2[(size_t)b * CAP2 + gp] = stage[s];
    else { int op = atomicAdd(ovcnt, 1); ovbuf[op & (NOV - 1)] = stage[s]; }
  }
  for (int b = t; b < NB2; b += 256) {
    int hvb = h[b], rvb = rsv[b], gb = gbase[b];
    for (int k = hvb; k < rvb; ++k) {
      int gp = gb + k;
      if (gp >= 0 && gp < CAP2) rec2[(size_t)b * CAP2 + gp] = 0xFFFFFFFFFFFFFFFFull;
    }
  }
}

__global__ __launch_bounds__(256) void cnt2(const int* __restrict__ bcur,
                                            const unsigned long long* __restrict__ rec2,
                                            const int* __restrict__ ovcnt,
                                            const unsigned long long* __restrict__ ovbuf,
                                            int* __restrict__ counts) {
  int b = blockIdx.x;
  __shared__ int c[512];
  int t = threadIdx.x;
  c[t] = 0; c[t + 256] = 0;
  __syncthreads();
  int nrec = bcur[b];
  nrec = nrec < CAP2 ? nrec : CAP2;
  const unsigned long long* rp = rec2 + (size_t)b * CAP2;
  for (int i = t; i < nrec; i += 256) {
    int gd = (int)(rp[i] >> 32);
    if (gd >= 0) atomicAdd(&c[gd & 511], 1);
  }
  int ovn = *ovcnt;
  ovn = ovn < NOV ? ovn : NOV;
  for (int i = t; i < ovn; i += 256) {
    int gd = (int)(ovbuf[i] >> 32);
    if (gd >= 0 && (gd >> BSH) == b) atomicAdd(&c[gd & 511], 1);
  }
  __syncthreads();
  int g0 = (b << BSH) + t;
  if (g0 < 70000) counts[g0] = c[t];
  int g1 = g0 + 256;
  if (g1 < 70000) counts[g1] = c[t + 256];
}

__global__ __launch_bounds__(256) void scan1(const int* __restrict__ cnt, int* __restrict__ out,
                                             int* __restrict__ part, int len) {
  __shared__ int sh[256];
  int base = blockIdx.x * 2048 + threadIdx.x * 8;
  int v[8];
  int s = 0;
  #pragma unroll
  for (int j = 0; j < 8; ++j) {
    int i = base + j;
    int x = (i < len) ? cnt[i] : 0;
    v[j] = s;
    s += x;
  }
  sh[threadIdx.x] = s;
  __syncthreads();
  for (int off = 1; off < 256; off <<= 1) {
    int t = (threadIdx.x >= off) ? sh[threadIdx.x - off] : 0;
    __syncthreads();
    sh[threadIdx.x] += t;
    __syncthreads();
  }
  int texcl = sh[threadIdx.x] - s;
  #pragma unroll
  for (int j = 0; j < 8; ++j) {
    int i = base + j;
    if (i < len) out[i] = texcl + v[j];
  }
  if (threadIdx.x == 255) part[blockIdx.x] = sh[255];
}

__global__ void scan2(int* __restrict__ part, int nb, int* __restrict__ total_out) {
  __shared__ int sh[64];
  int t = threadIdx.x;
  int v = (t < nb) ? part[t] : 0;
  sh[t] = v;
  __syncthreads();
  for (int off = 1; off < 64; off <<= 1) {
    int x = (t >= off) ? sh[t - off] : 0;
    __syncthreads();
    sh[t] += x;
    __syncthreads();
  }
  if (t < nb) part[t] = sh[t] - v;
  if (t == 63) *total_out = sh[63];
}

__global__ __launch_bounds__(256) void scan3(int* __restrict__ offs,
                                             const int* __restrict__ part, int len) {
  int i = blockIdx.x * 256 + threadIdx.x;
  if (i >= len) return;
  offs[i] += part[i >> 11];
}

__global__ __launch_bounds__(512) void fine2(const int* __restrict__ offs,
                                             const int* __restrict__ bcur,
                                             const unsigned long long* __restrict__ rec2,
                                             const int* __restrict__ ovcnt,
                                             const unsigned long long* __restrict__ ovbuf,
                                             unsigned int* __restrict__ pay) {
  int b = blockIdx.x;
  __shared__ int cur[512];
  int t = threadIdx.x;
  {
    int gd = (b << BSH) + t;
    cur[t] = (gd < 70000) ? offs[gd] : 0;
  }
  __syncthreads();
  int nrec = bcur[b];
  nrec = nrec < CAP2 ? nrec : CAP2;
  const unsigned long long* rp = rec2 + (size_t)b * CAP2;
  for (int i = t; i < nrec; i += 512) {
    unsigned long long r = rp[i];
    int gd = (int)(r >> 32);
    if (gd < 0) continue;             // sentinel pad
    int pos = atomicAdd(&cur[gd & 511], 1);
    if (pos >= 0 && pos < NPAY) pay[pos] = (unsigned)r;
  }
  int ovn = *ovcnt;
  ovn = ovn < NOV ? ovn : NOV;
  for (int i = t; i < ovn; i += 512) {
    unsigned long long r = ovbuf[i];
    int gd = (int)(r >> 32);
    if (gd >= 0 && (gd >> BSH) == b) {
      int pos = atomicAdd(&cur[gd & 511], 1);
      if (pos >= 0 && pos < NPAY) pay[pos] = (unsigned)r;
    }
  }
}

// all 6 relations; one wave per (dst, rel); 4 edges in flight (2 per half-wave)
struct Gather6 { const unsigned short* proj[6]; unsigned short* out[6]; int cb[6]; int n[6]; };
__global__ __launch_bounds__(256) void gather_all(Gather6 g, const int* __restrict__ offs,
                                                  const unsigned int* __restrict__ pay) {
  int rho = blockIdx.y;
  int n = g.n[rho];
  int d = blockIdx.x * 4 + (threadIdx.x >> 6);
  if (d >= n) return;
  int lane = threadIdx.x & 63, half = lane >> 5, l32 = lane & 31;
  const unsigned short* __restrict__ proj = g.proj[rho];
  const int* of = offs + g.cb[rho];
  int s0 = of[d], s1 = of[d + 1];
  float acc[8] = {};
  int e = s0 + half;
  for (; e + 2 < s1; e += 4) {
    unsigned int u0 = pay[e], u1 = pay[e + 2];
    float wt0 = bf2f((unsigned short)(u0 >> 16));
    float wt1 = bf2f((unsigned short)(u1 >> 16));
    s16x8 v0 = *(const s16x8*)(proj + (size_t)(u0 & 0xffffu) * 256 + l32 * 8);
    s16x8 v1 = *(const s16x8*)(proj + (size_t)(u1 & 0xffffu) * 256 + l32 * 8);
    #pragma unroll
    for (int j = 0; j < 8; ++j) {
      acc[j] = fmaf(bf2f((unsigned short)v0[j]), wt0, acc[j]);
      acc[j] = fmaf(bf2f((unsigned short)v1[j]), wt1, acc[j]);
    }
  }
  if (e < s1) {
    unsigned int u = pay[e];
    float wt = bf2f((unsigned short)(u >> 16));
    s16x8 v = *(const s16x8*)(proj + (size_t)(u & 0xffffu) * 256 + l32 * 8);
    #pragma unroll
    for (int j = 0; j < 8; ++j) acc[j] = fmaf(bf2f((unsigned short)v[j]), wt, acc[j]);
  }
  #pragma unroll
  for (int j = 0; j < 8; ++j) acc[j] += __shfl(acc[j], lane ^ 32, 64);
  if (half == 0) {
    s16x8 o;
    #pragma unroll
    for (int j = 0; j < 8; ++j) o[j] = (short)f2bf(acc[j]);
    *(s16x8*)(g.out[rho] + (size_t)d * 256 + l32 * 8) = o;
  }
}

// all 3 types: scores + FAITHFUL reshape(n,2) softmax over adjacent e-pairs
struct Att3 { const unsigned short* nb[3]; const unsigned short* self[3];
              const float* watt[3]; float* att[3]; int n[3]; };
__global__ __launch_bounds__(256) void e_att3(Att3 g) {
  int z = blockIdx.z;
  int n = g.n[z];
  int wv = threadIdx.x >> 6;
  int idx = blockIdx.x * 4 + wv;
  int lane = threadIdx.x & 63;
  __shared__ float ev[4];
  float sum = 0.f;
  if (idx < 2 * n) {
    int i = idx < n ? idx : idx - n;
    ushort4 v  = *(const ushort4*)(g.nb[z] + (size_t)idx * 256 + (lane << 2));
    ushort4 sv = *(const ushort4*)(g.self[z] + (size_t)i * 256 + (lane << 2));
    float4 wa = *(const float4*)(g.watt[z] + (lane << 2));
    float4 wb = *(const float4*)(g.watt[z] + 256 + (lane << 2));
    sum = bf2f(v.x) * wa.x + bf2f(v.y) * wa.y + bf2f(v.z) * wa.z + bf2f(v.w) * wa.w +
          bf2f(sv.x) * wb.x + bf2f(sv.y) * wb.y + bf2f(sv.z) * wb.z + bf2f(sv.w) * wb.w;
    #pragma unroll
    for (int off = 32; off > 0; off >>= 1) sum += __shfl_down(sum, off, 64);
  }
  if (lane == 0) ev[wv] = sum;
  __syncthreads();
  if (threadIdx.x < 2) {
    int base = blockIdx.x * 4 + threadIdx.x * 2;
    if (base < 2 * n) {
      float f0 = ev[threadIdx.x * 2], f1 = ev[threadIdx.x * 2 + 1];
      f0 = f0 > 0.f ? f0 : 0.01f * f0;
      f1 = f1 > 0.f ? f1 : 0.01f * f1;
      float m = fmaxf(f0, f1);
      float a = expf(f0 - m), b = expf(f1 - m);
      float inv = 1.f / (a + b);
      g.att[z][base] = a * inv;
      g.att[z][base + 1] = b * inv;
    }
  }
}

// all 3 types, BM=64/BN=256, 64x64 wave tiles, pipelined staging.
struct Fin3 { const unsigned short* nb[3]; const unsigned short* self[3]; const float* att[3];
              const unsigned short* Wt[3]; const float* bias[3]; float* out[3]; int M[3]; };
__global__ __launch_bounds__(256, 3) void final_mfma3(Fin3 g) {
  int z = blockIdx.z;
  int M = g.M[z];
  int row0 = blockIdx.y * 64;
  if (row0 >= M) return;
  const unsigned short* __restrict__ nbft = g.nb[z];
  const unsigned short* __restrict__ selfb = g.self[z];
  const float* __restrict__ att = g.att[z];
  const unsigned short* __restrict__ Wt = g.Wt[z];
  __shared__ unsigned short As[64 * 40];
  __shared__ unsigned short Bs[256 * 40];
  int tid = threadIdx.x, lane = tid & 63, w = tid >> 6;
  int quad = lane >> 4, m16 = lane & 15;
  int am = tid >> 2, akk = (tid & 3) * 8;
  int gr = row0 + am;
  float a0 = 0.f, a1 = 0.f;
  if (gr < M) { a0 = att[2 * gr]; a1 = att[2 * gr + 1]; }
  f32x4 acc[4][4];
  #pragma unroll
  for (int r = 0; r < 4; ++r)
    #pragma unroll
    for (int c = 0; c < 4; ++c) acc[r][c] = (f32x4){0.f, 0.f, 0.f, 0.f};

  s16x8 pu0 = {}, pu1 = {};
  s16x8 pb[4];

  auto loadA = [&](int k0) {
    int kg = k0 + akk;
    if (gr < M) {
      if (kg < 256) {
        pu0 = *(const s16x8*)(nbft + (size_t)gr * 256 + kg);
        pu1 = *(const s16x8*)(nbft + ((size_t)M + gr) * 256 + kg);
      } else {
        pu0 = *(const s16x8*)(selfb + (size_t)gr * 256 + (kg - 256));
      }
    }
  };
  auto loadB = [&](int k0) {
    #pragma unroll
    for (int i = 0; i < 4; ++i) {
      int ch = tid + i * 256;
      int m = ch >> 2, kk = (ch & 3) * 8;
      pb[i] = *(const s16x8*)(Wt + (size_t)m * 512 + k0 + kk);
    }
  };
  auto storeLDS = [&](int k0) {
    int kg = k0 + akk;
    s16x8 v = {};
    if (gr < M) {
      if (kg < 256) {
        #pragma unroll
        for (int j = 0; j < 8; ++j)
          v[j] = (short)f2bf(fmaf(a0, bf2f((unsigned short)pu0[j]),
                                  a1 * bf2f((unsigned short)pu1[j])));
      } else {
        v = pu0;
      }
    }
    *(s16x8*)&As[am * 40 + akk] = v;
    #pragma unroll
    for (int i = 0; i < 4; ++i) {
      int ch = tid + i * 256;
      int m = ch >> 2, kk = (ch & 3) * 8;
      *(s16x8*)&Bs[m * 40 + kk] = pb[i];
    }
  };

  loadA(0); loadB(0); storeLDS(0);
  __syncthreads();
  for (int k0 = 0; k0 < 512; k0 += 32) {
    int kn = k0 + 32;
    if (kn < 512) { loadA(kn); loadB(kn); }
    s16x8 af[4], bf[4];
    #pragma unroll
    for (int r = 0; r < 4; ++r)
      af[r] = *(const s16x8*)&As[(r * 16 + m16) * 40 + quad * 8];
    #pragma unroll
    for (int c = 0; c < 4; ++c)
      bf[c] = *(const s16x8*)&Bs[(w * 64 + c * 16 + m16) * 40 + quad * 8];
    #pragma unroll
    for (int r = 0; r < 4; ++r)
      #pragma unroll
      for (int c = 0; c < 4; ++c)
        acc[r][c] = __builtin_amdgcn_mfma_f32_16x16x32_bf16(af[r], bf[c], acc[r][c], 0, 0, 0);
    __syncthreads();
    if (kn < 512) {
      storeLDS(kn);
      __syncthreads();
    }
  }
  const float* __restrict__ bias = g.bias[z];
  float* __restrict__ out = g.out[z];
  #pragma unroll
  for (int r = 0; r < 4; ++r)
    #pragma unroll
    for (int i = 0; i < 4; ++i) {
      int row = row0 + r * 16 + quad * 4 + i;
      if (row < M) {
        #pragma unroll
        for (int c = 0; c < 4; ++c) {
          int col = w * 64 + c * 16 + m16;
          out[(size_t)row * 256 + col] = acc[r][c][i] + bias[col];
        }
      }
    }
}

} // namespace

extern "C" void kernel_launch(void* const* d_in, const int* in_sizes, int n_in,
                              void* d_out, int out_size, void* d_ws, size_t ws_size,
                              hipStream_t stream) {
  (void)in_sizes; (void)n_in; (void)out_size; (void)ws_size;
  const float* x[3] = {(const float*)d_in[0], (const float*)d_in[1], (const float*)d_in[2]};

  // ---- workspace layout ----
  char* p = (char*)d_ws;
  unsigned short* projfull = (unsigned short*)p;  p += (size_t)105000 * 256 * 2;
  unsigned short* nbft = (unsigned short*)p;      p += (size_t)70000 * 256 * 2;
  unsigned short* wcatbt = (unsigned short*)p;    p += (size_t)3 * 256 * 512 * 2;
  int* offs = (int*)p;                            p += (size_t)70004 * 4;
  int* counts = (int*)p;                          p += (size_t)70000 * 4;   // written by cnt2
  int* bcur = (int*)p;                            p += 160 * 4;             // zeroed
  int* ovcnt = (int*)p;                           p += 16;                  // zeroed
  int* part = (int*)p;                            p += 256;
  float* att_buf = (float*)p;                     p += (size_t)70000 * 4;
  unsigned int* csr_pay = (unsigned int*)p;       p += (size_t)1120000 * 4;
  // aliases into nbft (dead until gather_all):
  unsigned short* wshT = nbft;
  unsigned short* Wcbt = (unsigned short*)((char*)nbft + 393216);
  // record buffers alias projfull (dead until proj_mfma6 overwrites all rows):
  unsigned long long* rec2 = (unsigned long long*)projfull;            // 18 MB
  unsigned long long* ovbuf = rec2 + (size_t)NB2 * CAP2;               // 0.5 MB
  // bf16 copy of x lives in d_out (dead until final_mfma3 writes real output):
  unsigned short* xb = (unsigned short*)d_out;

  const int n_of[3] = {20000, 10000, 5000};
  const int nbt[3][2] = {{1, 2}, {0, 2}, {0, 1}};
  const int ebase[3][2] = {{3, 6}, {9, 12}, {15, 18}};
  const int nE3[3] = {320000, 160000, 80000};
  const size_t out_off[3] = {0, (size_t)20000 * 256, (size_t)30000 * 256};
  const int tstart[3] = {0, 15000, 40000};
  const int selfoff[3] = {70000, 90000, 100000};
  const int nboff[3] = {0, 40000, 60000};
  const int xboff[3] = {0, 20000, 30000};

  // ---- x -> bf16 ----
  cvt_x3<<<dim3(8750), 256, 0, stream>>>(x[0], x[1], x[2], xb);

  // ---- transpose+cvt: 3 wsh, 3 wcat ----
  Tc6 tc;
  for (int t = 0; t < 3; ++t) {
    tc.src[t] = (const float*)d_in[21 + t * 7 + 3];
    tc.dst[t] = wshT + (size_t)t * 256 * 256;
    tc.R[t] = 256;
    tc.src[3 + t] = (const float*)d_in[21 + t * 7 + 5];
    tc.dst[3 + t] = wcatbt + (size_t)t * 256 * 512;
    tc.R[3 + t] = 512;
  }
  transpose_cvt<<<dim3(8, 16, 6), 256, 0, stream>>>(tc);

  // ---- combined weights via MFMA ----
  Comb9 c9;
  for (int t = 0; t < 3; ++t) {
    int wb = 21 + t * 7;
    for (int j = 0; j < 3; ++j) {
      int combo = t * 3 + j;
      c9.A[combo] = wshT + (size_t)t * 256 * 256;
      c9.B[combo] = (const float*)d_in[wb + j];
      c9.C[combo] = Wcbt + (size_t)combo * 256 * 512;
    }
  }
  combine_mfma<<<dim3(4, 2, 9), 256, 0, stream>>>(c9);

  // ---- CSR build (LDS-staged two-level counting sort) ----
  Edges6 ep;
  const int cbase[6] = {0, 20000, 40000, 50000, 60000, 65000};
  for (int t = 0; t < 3; ++t)
    for (int r = 0; r < 2; ++r) {
      int rho = t * 2 + r, eb = ebase[t][r];
      ep.src[rho] = (const int*)d_in[eb];
      ep.dst[rho] = (const int*)d_in[eb + 1];
      ep.w[rho] = (const float*)d_in[eb + 2];
      ep.nE[rho] = nE3[t];
      ep.cbase[rho] = cbase[rho];
    }
  hipMemsetAsync(bcur, 0, 160 * 4 + 16, stream);
  bin1<<<dim3(313, 6), 256, 0, stream>>>(ep, bcur, ovcnt, rec2, ovbuf);
  cnt2<<<NB2, 256, 0, stream>>>(bcur, rec2, ovcnt, ovbuf, counts);
  scan1<<<35, 256, 0, stream>>>(counts, offs, part, 70000);
  scan2<<<1, 64, 0, stream>>>(part, 35, offs + 70000);
  scan3<<<274, 256, 0, stream>>>(offs, part, 70000);
  fine2<<<NB2, 512, 0, stream>>>(offs, bcur, rec2, ovcnt, ovbuf, csr_pay);

  // ---- projections: source-keyed, XCD-swizzled 1D grid ----
  Proj3 pj;
  {
    int cnum[3] = {0, 0, 0};
    for (int t = 0; t < 3; ++t) {
      int m0 = n_of[nbt[t][0]];
      for (int j = 0; j < 3; ++j) {
        int s = (j == 2) ? t : nbt[t][j];
        unsigned short* dst =
            (j == 0) ? projfull + (size_t)tstart[t] * 256
          : (j == 1) ? projfull + (size_t)(tstart[t] + m0) * 256
                     : projfull + (size_t)selfoff[t] * 256;
        int c = cnum[s]++;
        pj.Bt[s][c] = Wcbt + (size_t)(t * 3 + j) * 256 * 512;
        pj.C[s][c] = dst;
      }
    }
    for (int s = 0; s < 3; ++s) {
      pj.A[s] = xb + (size_t)xboff[s] * 512;
      pj.M[s] = n_of[s];
    }
  }
  proj_mfma6<<<dim3(PROJ_NWG), 256, 0, stream>>>(pj);

  // ---- all 6 gathers, one launch ----
  Gather6 gt;
  for (int t = 0; t < 3; ++t) {
    int m0 = n_of[nbt[t][0]];
    for (int r = 0; r < 2; ++r) {
      int rho = t * 2 + r;
      gt.proj[rho] = projfull + (size_t)(tstart[t] + (r ? m0 : 0)) * 256;
      gt.out[rho] = nbft + (size_t)(nboff[t] + r * n_of[t]) * 256;
      gt.cb[rho] = cbase[rho];
      gt.n[rho] = n_of[t];
    }
  }
  gather_all<<<dim3(5000, 6), 256, 0, stream>>>(gt, offs, csr_pay);

  // ---- attention (3 types) ----
  Att3 at;
  for (int t = 0; t < 3; ++t) {
    at.nb[t] = nbft + (size_t)nboff[t] * 256;
    at.self[t] = projfull + (size_t)selfoff[t] * 256;
    at.watt[t] = (const float*)d_in[21 + t * 7 + 4];
    at.att[t] = att_buf + nboff[t];
    at.n[t] = n_of[t];
  }
  e_att3<<<dim3(10000, 1, 3), 256, 0, stream>>>(at);

  // ---- final GEMM (3 types, BM=64, 64x64 wave tiles) ----
  Fin3 fn;
  for (int t = 0; t < 3; ++t) {
    fn.nb[t] = nbft + (size_t)nboff[t] * 256;
    fn.self[t] = projfull + (size_t)selfoff[t] * 256;
    fn.att[t] = att_buf + nboff[t];
    fn.Wt[t] = wcatbt + (size_t)t * 256 * 512;
    fn.bias[t] = (const float*)d_in[21 + t * 7 + 6];
    fn.out[t] = (float*)d_out + out_off[t];
    fn.M[t] = n_of[t];
  }
  final_mfma3<<<dim3(1, 313, 3), 256, 0, stream>>>(fn);
}

// Round 11
// 401.597 us; speedup vs baseline: 1.0560x; 1.0560x over previous
//
#include <hip/hip_runtime.h>

namespace {

typedef short s16x8 __attribute__((ext_vector_type(8)));
typedef float f32x4 __attribute__((ext_vector_type(4)));

__device__ __forceinline__ float bf2f(unsigned short u) {
  return __uint_as_float(((unsigned)u) << 16);
}
__device__ __forceinline__ unsigned short f2bf(float f) {
  unsigned u = __float_as_uint(f);
  u += 0x7fffu + ((u >> 16) & 1u);
  return (unsigned short)(u >> 16);
}

// async global->LDS, 16B per lane. LDS dest is wave-uniform base + lane*16.
typedef __attribute__((address_space(3))) unsigned int lds_u32;
typedef __attribute__((address_space(1))) const unsigned int glob_u32;
__device__ __forceinline__ void gl16(const void* g, void* l) {
  __builtin_amdgcn_global_load_lds((glob_u32*)g, (lds_u32*)l, 16, 0, 0);
}

// x (fp32) -> xb (bf16), 35000x512 total; xb lives in d_out (dead until final_mfma3).
__global__ __launch_bounds__(256) void cvt_x3(const float* __restrict__ x0,
                                              const float* __restrict__ x1,
                                              const float* __restrict__ x2,
                                              unsigned short* __restrict__ out) {
  size_t i = ((size_t)blockIdx.x * 256 + threadIdx.x) * 8;
  const float* src;
  size_t off;
  if (i < (size_t)20000 * 512) { src = x0; off = i; }
  else if (i < (size_t)30000 * 512) { src = x1; off = i - (size_t)20000 * 512; }
  else { src = x2; off = i - (size_t)30000 * 512; }
  float4 a = *(const float4*)(src + off);
  float4 b = *(const float4*)(src + off + 4);
  s16x8 v;
  v[0] = (short)f2bf(a.x); v[1] = (short)f2bf(a.y);
  v[2] = (short)f2bf(a.z); v[3] = (short)f2bf(a.w);
  v[4] = (short)f2bf(b.x); v[5] = (short)f2bf(b.y);
  v[6] = (short)f2bf(b.z); v[7] = (short)f2bf(b.w);
  *(s16x8*)(out + i) = v;
}

// fp32 [R][256] -> bf16 [256][R] (transposed). wsh: R=256, wcat: R=512.
struct Tc6 { const float* src[6]; unsigned short* dst[6]; int R[6]; };
__global__ __launch_bounds__(256) void transpose_cvt(Tc6 a) {
  int mat = blockIdx.z;
  int R = a.R[mat];
  int r0 = blockIdx.y * 32, c0 = blockIdx.x * 32;
  if (r0 >= R) return;
  const float* __restrict__ src = a.src[mat];
  unsigned short* __restrict__ dst = a.dst[mat];
  __shared__ float T[32][33];
  int tx = threadIdx.x & 31, ty = threadIdx.x >> 5;
  #pragma unroll
  for (int j = 0; j < 4; ++j) {
    int r = ty + j * 8;
    T[r][tx] = src[(size_t)(r0 + r) * 256 + c0 + tx];
  }
  __syncthreads();
  #pragma unroll
  for (int j = 0; j < 4; ++j) {
    int c = ty + j * 8;
    dst[(size_t)(c0 + c) * R + r0 + tx] = f2bf(T[tx][c]);
  }
}

// Wcbt[256x512] = wshT[256x256](bf16) @ W[512x256]^T(fp32, cvt on load)
struct Comb9 { const unsigned short* A[9]; const float* B[9]; unsigned short* C[9]; };
__global__ __launch_bounds__(256) void combine_mfma(Comb9 g) {
  int z = blockIdx.z;
  const unsigned short* __restrict__ A = g.A[z];
  const float* __restrict__ B = g.B[z];
  unsigned short* __restrict__ C = g.C[z];
  int row0 = blockIdx.y * 128;
  int col0 = blockIdx.x * 128;
  __shared__ unsigned short As[128 * 40];
  __shared__ unsigned short Bs[128 * 40];
  int tid = threadIdx.x, lane = tid & 63, w = tid >> 6;
  int quad = lane >> 4, m16 = lane & 15;
  f32x4 acc[2][8];
  #pragma unroll
  for (int r = 0; r < 2; ++r)
    #pragma unroll
    for (int c = 0; c < 8; ++c) acc[r][c] = (f32x4){0.f, 0.f, 0.f, 0.f};
  for (int k0 = 0; k0 < 256; k0 += 32) {
    #pragma unroll
    for (int i = 0; i < 2; ++i) {
      int ch = tid + i * 256;
      int m = ch >> 2, kk = (ch & 3) * 8;
      *(s16x8*)&As[m * 40 + kk] = *(const s16x8*)(A + (size_t)(row0 + m) * 256 + k0 + kk);
      const float4* bp = (const float4*)(B + (size_t)(col0 + m) * 256 + k0 + kk);
      float4 b0 = bp[0], b1 = bp[1];
      s16x8 bv;
      bv[0] = (short)f2bf(b0.x); bv[1] = (short)f2bf(b0.y);
      bv[2] = (short)f2bf(b0.z); bv[3] = (short)f2bf(b0.w);
      bv[4] = (short)f2bf(b1.x); bv[5] = (short)f2bf(b1.y);
      bv[6] = (short)f2bf(b1.z); bv[7] = (short)f2bf(b1.w);
      *(s16x8*)&Bs[m * 40 + kk] = bv;
    }
    __syncthreads();
    s16x8 af[2], bf[8];
    #pragma unroll
    for (int r = 0; r < 2; ++r)
      af[r] = *(const s16x8*)&As[(w * 32 + r * 16 + m16) * 40 + quad * 8];
    #pragma unroll
    for (int c = 0; c < 8; ++c)
      bf[c] = *(const s16x8*)&Bs[(c * 16 + m16) * 40 + quad * 8];
    #pragma unroll
    for (int r = 0; r < 2; ++r)
      #pragma unroll
      for (int c = 0; c < 8; ++c)
        acc[r][c] = __builtin_amdgcn_mfma_f32_16x16x32_bf16(af[r], bf[c], acc[r][c], 0, 0, 0);
    __syncthreads();
  }
  #pragma unroll
  for (int r = 0; r < 2; ++r)
    #pragma unroll
    for (int i = 0; i < 4; ++i) {
      int row = row0 + w * 32 + r * 16 + quad * 4 + i;
      #pragma unroll
      for (int c = 0; c < 8; ++c)
        C[(size_t)row * 512 + col0 + c * 16 + m16] = f2bf(acc[r][c][i]);
    }
}

// Projections: r7 block shape + XCD swizzle over a DENSE (hole-free) work space.
// r10 post-mortem: swizzle over the padded 2826-wg space gave XCD0 353 valid
// tiles while tail XCDs got mostly early-exit holes -> load imbalance (73us)
// despite FETCH 112->25MB. Dense space: s=0 tiles [0,942), s=1 [942,1416)
// (79 y-tiles), s=2 [1416,1656) (40 y-tiles). NWG=1656=8*207 exactly ->
// wg=(orig&7)*207+(orig>>3): every XCD gets 207 valid panel-contiguous tiles.
// SQ_LDS_BANK_CONFLICT ~3.4M is the gl16-write intrinsic itself (r7=r9
// identical, r8 exactly 0.75x with 0.75x gl16 ops) -- not actionable.
#define PROJ_NWG 1656
struct Proj3 { const unsigned short* A[3]; const unsigned short* Bt[3][3];
               unsigned short* C[3][3]; int M[3]; };
__global__ __launch_bounds__(256) void proj_mfma6(Proj3 g) {
  int orig = blockIdx.x;
  int wg = (orig & 7) * 207 + (orig >> 3);   // bijective: 1656 % 8 == 0
  int s, rem;
  if (wg < 942) { s = 0; rem = wg; }
  else if (wg < 1416) { s = 1; rem = wg - 942; }
  else { s = 2; rem = wg - 1416; }
  int by = rem / 6;
  int bx = rem - by * 6;
  int M = g.M[s];
  int row0 = by * 128;
  if (row0 >= M) return;                     // defensive (dense space: unreachable)
  int combo = bx >> 1;
  int col0 = (bx & 1) * 128;
  const unsigned short* __restrict__ A = g.A[s];
  const unsigned short* __restrict__ Bt = g.Bt[s][combo];   // 256 x 512
  unsigned short* __restrict__ C = g.C[s][combo];           // M x 256
  __shared__ unsigned short As[128 * 32];
  __shared__ unsigned short Bs[128 * 32];
  int tid = threadIdx.x, lane = tid & 63, w = tid >> 6;
  int quad = lane >> 4, m16 = lane & 15;
  int lr = lane >> 2;
  // pre-swizzled global k-chunk (elements)
  int lk = (((lane & 3) ^ (lr & 3) ^ ((lr >> 2) & 3))) * 8;
  int ar0 = row0 + w * 32 + lr;
  int ar1 = ar0 + 16;
  const unsigned short* a0p = A + (size_t)(ar0 < M ? ar0 : M - 1) * 512 + lk;
  const unsigned short* a1p = A + (size_t)(ar1 < M ? ar1 : M - 1) * 512 + lk;
  const unsigned short* b0p = Bt + (size_t)(col0 + w * 32 + lr) * 512 + lk;
  const unsigned short* b1p = b0p + (size_t)16 * 512;
  unsigned short* as0 = &As[w * 1024];
  unsigned short* as1 = &As[w * 1024 + 512];
  unsigned short* bs0 = &Bs[w * 1024];
  unsigned short* bs1 = &Bs[w * 1024 + 512];
  int wr = (w & 1) * 64, wc = (w >> 1) * 64;
  // swizzled read k-chunk (elements)
  int sw = ((quad ^ (m16 & 3) ^ ((m16 >> 2) & 3))) * 8;
  f32x4 acc[4][4];
  #pragma unroll
  for (int r = 0; r < 4; ++r)
    #pragma unroll
    for (int c = 0; c < 4; ++c) acc[r][c] = (f32x4){0.f, 0.f, 0.f, 0.f};
  for (int k0 = 0; k0 < 512; k0 += 32) {
    gl16(a0p + k0, as0);
    gl16(a1p + k0, as1);
    gl16(b0p + k0, bs0);
    gl16(b1p + k0, bs1);
    __syncthreads();
    s16x8 af[4], bf[4];
    #pragma unroll
    for (int r = 0; r < 4; ++r)
      af[r] = *(const s16x8*)&As[(wr + r * 16 + m16) * 32 + sw];
    #pragma unroll
    for (int c = 0; c < 4; ++c)
      bf[c] = *(const s16x8*)&Bs[(wc + c * 16 + m16) * 32 + sw];
    #pragma unroll
    for (int r = 0; r < 4; ++r)
      #pragma unroll
      for (int c = 0; c < 4; ++c)
        acc[r][c] = __builtin_amdgcn_mfma_f32_16x16x32_bf16(af[r], bf[c], acc[r][c], 0, 0, 0);
    __syncthreads();
  }
  #pragma unroll
  for (int r = 0; r < 4; ++r)
    #pragma unroll
    for (int i = 0; i < 4; ++i) {
      int row = row0 + wr + r * 16 + quad * 4 + i;
      if (row < M) {
        #pragma unroll
        for (int c = 0; c < 4; ++c)
          C[(size_t)row * 256 + col0 + wc + c * 16 + m16] = f2bf(acc[r][c][i]);
      }
    }
}

struct Edges6 { const int* src[6]; const int* dst[6]; const float* w[6]; int nE[6]; int cbase[6]; };

// ---- CSR build: LDS-staged two-level counting sort ----
#define BSH 9
#define NB2 137            // ceil(70000 / 512)
#define CAP2 16384         // padded mean ~12.3K; huge margin + overflow path
#define NOV 65536
#define CH 1024
#define NPAY 1120000

__global__ __launch_bounds__(256) void bin1(Edges6 ep,
                                            int* __restrict__ bcur, int* __restrict__ ovcnt,
                                            unsigned long long* __restrict__ rec2,
                                            unsigned long long* __restrict__ ovbuf) {
  int rho = blockIdx.y;
  int nE = ep.nE[rho];
  int chunk = blockIdx.x * CH;
  if (chunk >= nE) return;
  int n = nE - chunk; if (n > CH) n = CH;
  const int* __restrict__ srcp = ep.src[rho];
  const int* __restrict__ dstp = ep.dst[rho];
  const float* __restrict__ wp = ep.w[rho];
  int cb = ep.cbase[rho];
  __shared__ int h[256], excl[256], lcur[256], gbase[256], rsv[256];
  __shared__ int wsum[4];
  __shared__ unsigned long long stage[CH];
  int t = threadIdx.x;
  h[t] = 0;
  gbase[t] = 0;
  __syncthreads();
  int gd[4]; unsigned pv[4];
  #pragma unroll
  for (int j = 0; j < 4; ++j) {
    int idx = t + j * 256;
    gd[j] = -1;
    if (idx < n) {
      int e = chunk + idx;
      int g = cb + dstp[e];
      if (g < 0) g = 0;
      if (g > 69999) g = 69999;       // defensive (inputs guarantee in-range)
      gd[j] = g;
      pv[j] = (((unsigned)f2bf(wp[e])) << 16) | ((unsigned)srcp[e] & 0x7fffu);
      atomicAdd(&h[g >> BSH], 1);
    }
  }
  __syncthreads();
  int hv = h[t];
  int lane = t & 63, wv = t >> 6;
  int v = hv;
  #pragma unroll
  for (int off = 1; off < 64; off <<= 1) {
    int u = __shfl_up(v, off, 64);
    if (lane >= off) v += u;
  }
  if (lane == 63) wsum[wv] = v;
  __syncthreads();
  int add = 0;
  #pragma unroll
  for (int k = 0; k < 3; ++k)
    if (k < wv) add += wsum[k];
  v += add;
  int ex = v - hv;
  excl[t] = ex;
  lcur[t] = ex;
  int rv = 0;
  if (t < NB2 && hv > 0) {
    rv = (hv + 7) & ~7;               // 64B-aligned reservation
    gbase[t] = atomicAdd(&bcur[t], rv);
  }
  rsv[t] = rv;
  __syncthreads();
  #pragma unroll
  for (int j = 0; j < 4; ++j) {
    if (gd[j] >= 0) {
      int b = gd[j] >> BSH;
      int slot = atomicAdd(&lcur[b], 1);
      if (slot >= 0 && slot < CH)
        stage[slot] = ((unsigned long long)(unsigned)gd[j] << 32) | pv[j];
    }
  }
  __syncthreads();
  for (int s = t; s < n; s += 256) {
    int lo = 0, hi = NB2 - 1;
    while (lo < hi) {
      int mid = (lo + hi + 1) >> 1;
      if (excl[mid] <= s) lo = mid; else hi = mid - 1;
    }
    int b = lo;
    int gp = gbase[b] + (s - excl[b]);
    if (gp >= 0 && gp < CAP2) rec2[(size_t)b * CAP2 + gp] = stage[s];
    else { int op = atomicAdd(ovcnt, 1); ovbuf[op & (NOV - 1)] = stage[s]; }
  }
  for (int b = t; b < NB2; b += 256) {
    int hvb = h[b], rvb = rsv[b], gb = gbase[b];
    for (int k = hvb; k < rvb; ++k) {
      int gp = gb + k;
      if (gp >= 0 && gp < CAP2) rec2[(size_t)b * CAP2 + gp] = 0xFFFFFFFFFFFFFFFFull;
    }
  }
}

__global__ __launch_bounds__(256) void cnt2(const int* __restrict__ bcur,
                                            const unsigned long long* __restrict__ rec2,
                                            const int* __restrict__ ovcnt,
                                            const unsigned long long* __restrict__ ovbuf,
                                            int* __restrict__ counts) {
  int b = blockIdx.x;
  __shared__ int c[512];
  int t = threadIdx.x;
  c[t] = 0; c[t + 256] = 0;
  __syncthreads();
  int nrec = bcur[b];
  nrec = nrec < CAP2 ? nrec : CAP2;
  const unsigned long long* rp = rec2 + (size_t)b * CAP2;
  for (int i = t; i < nrec; i += 256) {
    int gd = (int)(rp[i] >> 32);
    if (gd >= 0) atomicAdd(&c[gd & 511], 1);
  }
  int ovn = *ovcnt;
  ovn = ovn < NOV ? ovn : NOV;
  for (int i = t; i < ovn; i += 256) {
    int gd = (int)(ovbuf[i] >> 32);
    if (gd >= 0 && (gd >> BSH) == b) atomicAdd(&c[gd & 511], 1);
  }
  __syncthreads();
  int g0 = (b << BSH) + t;
  if (g0 < 70000) counts[g0] = c[t];
  int g1 = g0 + 256;
  if (g1 < 70000) counts[g1] = c[t + 256];
}

__global__ __launch_bounds__(256) void scan1(const int* __restrict__ cnt, int* __restrict__ out,
                                             int* __restrict__ part, int len) {
  __shared__ int sh[256];
  int base = blockIdx.x * 2048 + threadIdx.x * 8;
  int v[8];
  int s = 0;
  #pragma unroll
  for (int j = 0; j < 8; ++j) {
    int i = base + j;
    int x = (i < len) ? cnt[i] : 0;
    v[j] = s;
    s += x;
  }
  sh[threadIdx.x] = s;
  __syncthreads();
  for (int off = 1; off < 256; off <<= 1) {
    int t = (threadIdx.x >= off) ? sh[threadIdx.x - off] : 0;
    __syncthreads();
    sh[threadIdx.x] += t;
    __syncthreads();
  }
  int texcl = sh[threadIdx.x] - s;
  #pragma unroll
  for (int j = 0; j < 8; ++j) {
    int i = base + j;
    if (i < len) out[i] = texcl + v[j];
  }
  if (threadIdx.x == 255) part[blockIdx.x] = sh[255];
}

__global__ void scan2(int* __restrict__ part, int nb, int* __restrict__ total_out) {
  __shared__ int sh[64];
  int t = threadIdx.x;
  int v = (t < nb) ? part[t] : 0;
  sh[t] = v;
  __syncthreads();
  for (int off = 1; off < 64; off <<= 1) {
    int x = (t >= off) ? sh[t - off] : 0;
    __syncthreads();
    sh[t] += x;
    __syncthreads();
  }
  if (t < nb) part[t] = sh[t] - v;
  if (t == 63) *total_out = sh[63];
}

__global__ __launch_bounds__(256) void scan3(int* __restrict__ offs,
                                             const int* __restrict__ part, int len) {
  int i = blockIdx.x * 256 + threadIdx.x;
  if (i >= len) return;
  offs[i] += part[i >> 11];
}

__global__ __launch_bounds__(512) void fine2(const int* __restrict__ offs,
                                             const int* __restrict__ bcur,
                                             const unsigned long long* __restrict__ rec2,
                                             const int* __restrict__ ovcnt,
                                             const unsigned long long* __restrict__ ovbuf,
                                             unsigned int* __restrict__ pay) {
  int b = blockIdx.x;
  __shared__ int cur[512];
  int t = threadIdx.x;
  {
    int gd = (b << BSH) + t;
    cur[t] = (gd < 70000) ? offs[gd] : 0;
  }
  __syncthreads();
  int nrec = bcur[b];
  nrec = nrec < CAP2 ? nrec : CAP2;
  const unsigned long long* rp = rec2 + (size_t)b * CAP2;
  for (int i = t; i < nrec; i += 512) {
    unsigned long long r = rp[i];
    int gd = (int)(r >> 32);
    if (gd < 0) continue;             // sentinel pad
    int pos = atomicAdd(&cur[gd & 511], 1);
    if (pos >= 0 && pos < NPAY) pay[pos] = (unsigned)r;
  }
  int ovn = *ovcnt;
  ovn = ovn < NOV ? ovn : NOV;
  for (int i = t; i < ovn; i += 512) {
    unsigned long long r = ovbuf[i];
    int gd = (int)(r >> 32);
    if (gd >= 0 && (gd >> BSH) == b) {
      int pos = atomicAdd(&cur[gd & 511], 1);
      if (pos >= 0 && pos < NPAY) pay[pos] = (unsigned)r;
    }
  }
}

// all 6 relations; one wave per (dst, rel); 4 edges in flight (2 per half-wave)
struct Gather6 { const unsigned short* proj[6]; unsigned short* out[6]; int cb[6]; int n[6]; };
__global__ __launch_bounds__(256) void gather_all(Gather6 g, const int* __restrict__ offs,
                                                  const unsigned int* __restrict__ pay) {
  int rho = blockIdx.y;
  int n = g.n[rho];
  int d = blockIdx.x * 4 + (threadIdx.x >> 6);
  if (d >= n) return;
  int lane = threadIdx.x & 63, half = lane >> 5, l32 = lane & 31;
  const unsigned short* __restrict__ proj = g.proj[rho];
  const int* of = offs + g.cb[rho];
  int s0 = of[d], s1 = of[d + 1];
  float acc[8] = {};
  int e = s0 + half;
  for (; e + 2 < s1; e += 4) {
    unsigned int u0 = pay[e], u1 = pay[e + 2];
    float wt0 = bf2f((unsigned short)(u0 >> 16));
    float wt1 = bf2f((unsigned short)(u1 >> 16));
    s16x8 v0 = *(const s16x8*)(proj + (size_t)(u0 & 0xffffu) * 256 + l32 * 8);
    s16x8 v1 = *(const s16x8*)(proj + (size_t)(u1 & 0xffffu) * 256 + l32 * 8);
    #pragma unroll
    for (int j = 0; j < 8; ++j) {
      acc[j] = fmaf(bf2f((unsigned short)v0[j]), wt0, acc[j]);
      acc[j] = fmaf(bf2f((unsigned short)v1[j]), wt1, acc[j]);
    }
  }
  if (e < s1) {
    unsigned int u = pay[e];
    float wt = bf2f((unsigned short)(u >> 16));
    s16x8 v = *(const s16x8*)(proj + (size_t)(u & 0xffffu) * 256 + l32 * 8);
    #pragma unroll
    for (int j = 0; j < 8; ++j) acc[j] = fmaf(bf2f((unsigned short)v[j]), wt, acc[j]);
  }
  #pragma unroll
  for (int j = 0; j < 8; ++j) acc[j] += __shfl(acc[j], lane ^ 32, 64);
  if (half == 0) {
    s16x8 o;
    #pragma unroll
    for (int j = 0; j < 8; ++j) o[j] = (short)f2bf(acc[j]);
    *(s16x8*)(g.out[rho] + (size_t)d * 256 + l32 * 8) = o;
  }
}

// all 3 types: scores + FAITHFUL reshape(n,2) softmax over adjacent e-pairs
struct Att3 { const unsigned short* nb[3]; const unsigned short* self[3];
              const float* watt[3]; float* att[3]; int n[3]; };
__global__ __launch_bounds__(256) void e_att3(Att3 g) {
  int z = blockIdx.z;
  int n = g.n[z];
  int wv = threadIdx.x >> 6;
  int idx = blockIdx.x * 4 + wv;
  int lane = threadIdx.x & 63;
  __shared__ float ev[4];
  float sum = 0.f;
  if (idx < 2 * n) {
    int i = idx < n ? idx : idx - n;
    ushort4 v  = *(const ushort4*)(g.nb[z] + (size_t)idx * 256 + (lane << 2));
    ushort4 sv = *(const ushort4*)(g.self[z] + (size_t)i * 256 + (lane << 2));
    float4 wa = *(const float4*)(g.watt[z] + (lane << 2));
    float4 wb = *(const float4*)(g.watt[z] + 256 + (lane << 2));
    sum = bf2f(v.x) * wa.x + bf2f(v.y) * wa.y + bf2f(v.z) * wa.z + bf2f(v.w) * wa.w +
          bf2f(sv.x) * wb.x + bf2f(sv.y) * wb.y + bf2f(sv.z) * wb.z + bf2f(sv.w) * wb.w;
    #pragma unroll
    for (int off = 32; off > 0; off >>= 1) sum += __shfl_down(sum, off, 64);
  }
  if (lane == 0) ev[wv] = sum;
  __syncthreads();
  if (threadIdx.x < 2) {
    int base = blockIdx.x * 4 + threadIdx.x * 2;
    if (base < 2 * n) {
      float f0 = ev[threadIdx.x * 2], f1 = ev[threadIdx.x * 2 + 1];
      f0 = f0 > 0.f ? f0 : 0.01f * f0;
      f1 = f1 > 0.f ? f1 : 0.01f * f1;
      float m = fmaxf(f0, f1);
      float a = expf(f0 - m), b = expf(f1 - m);
      float inv = 1.f / (a + b);
      g.att[z][base] = a * inv;
      g.att[z][base + 1] = b * inv;
    }
  }
}

// all 3 types, BM=64/BN=256, 64x64 wave tiles, pipelined staging.
struct Fin3 { const unsigned short* nb[3]; const unsigned short* self[3]; const float* att[3];
              const unsigned short* Wt[3]; const float* bias[3]; float* out[3]; int M[3]; };
__global__ __launch_bounds__(256, 3) void final_mfma3(Fin3 g) {
  int z = blockIdx.z;
  int M = g.M[z];
  int row0 = blockIdx.y * 64;
  if (row0 >= M) return;
  const unsigned short* __restrict__ nbft = g.nb[z];
  const unsigned short* __restrict__ selfb = g.self[z];
  const float* __restrict__ att = g.att[z];
  const unsigned short* __restrict__ Wt = g.Wt[z];
  __shared__ unsigned short As[64 * 40];
  __shared__ unsigned short Bs[256 * 40];
  int tid = threadIdx.x, lane = tid & 63, w = tid >> 6;
  int quad = lane >> 4, m16 = lane & 15;
  int am = tid >> 2, akk = (tid & 3) * 8;
  int gr = row0 + am;
  float a0 = 0.f, a1 = 0.f;
  if (gr < M) { a0 = att[2 * gr]; a1 = att[2 * gr + 1]; }
  f32x4 acc[4][4];
  #pragma unroll
  for (int r = 0; r < 4; ++r)
    #pragma unroll
    for (int c = 0; c < 4; ++c) acc[r][c] = (f32x4){0.f, 0.f, 0.f, 0.f};

  s16x8 pu0 = {}, pu1 = {};
  s16x8 pb[4];

  auto loadA = [&](int k0) {
    int kg = k0 + akk;
    if (gr < M) {
      if (kg < 256) {
        pu0 = *(const s16x8*)(nbft + (size_t)gr * 256 + kg);
        pu1 = *(const s16x8*)(nbft + ((size_t)M + gr) * 256 + kg);
      } else {
        pu0 = *(const s16x8*)(selfb + (size_t)gr * 256 + (kg - 256));
      }
    }
  };
  auto loadB = [&](int k0) {
    #pragma unroll
    for (int i = 0; i < 4; ++i) {
      int ch = tid + i * 256;
      int m = ch >> 2, kk = (ch & 3) * 8;
      pb[i] = *(const s16x8*)(Wt + (size_t)m * 512 + k0 + kk);
    }
  };
  auto storeLDS = [&](int k0) {
    int kg = k0 + akk;
    s16x8 v = {};
    if (gr < M) {
      if (kg < 256) {
        #pragma unroll
        for (int j = 0; j < 8; ++j)
          v[j] = (short)f2bf(fmaf(a0, bf2f((unsigned short)pu0[j]),
                                  a1 * bf2f((unsigned short)pu1[j])));
      } else {
        v = pu0;
      }
    }
    *(s16x8*)&As[am * 40 + akk] = v;
    #pragma unroll
    for (int i = 0; i < 4; ++i) {
      int ch = tid + i * 256;
      int m = ch >> 2, kk = (ch & 3) * 8;
      *(s16x8*)&Bs[m * 40 + kk] = pb[i];
    }
  };

  loadA(0); loadB(0); storeLDS(0);
  __syncthreads();
  for (int k0 = 0; k0 < 512; k0 += 32) {
    int kn = k0 + 32;
    if (kn < 512) { loadA(kn); loadB(kn); }
    s16x8 af[4], bf[4];
    #pragma unroll
    for (int r = 0; r < 4; ++r)
      af[r] = *(const s16x8*)&As[(r * 16 + m16) * 40 + quad * 8];
    #pragma unroll
    for (int c = 0; c < 4; ++c)
      bf[c] = *(const s16x8*)&Bs[(w * 64 + c * 16 + m16) * 40 + quad * 8];
    #pragma unroll
    for (int r = 0; r < 4; ++r)
      #pragma unroll
      for (int c = 0; c < 4; ++c)
        acc[r][c] = __builtin_amdgcn_mfma_f32_16x16x32_bf16(af[r], bf[c], acc[r][c], 0, 0, 0);
    __syncthreads();
    if (kn < 512) {
      storeLDS(kn);
      __syncthreads();
    }
  }
  const float* __restrict__ bias = g.bias[z];
  float* __restrict__ out = g.out[z];
  #pragma unroll
  for (int r = 0; r < 4; ++r)
    #pragma unroll
    for (int i = 0; i < 4; ++i) {
      int row = row0 + r * 16 + quad * 4 + i;
      if (row < M) {
        #pragma unroll
        for (int c = 0; c < 4; ++c) {
          int col = w * 64 + c * 16 + m16;
          out[(size_t)row * 256 + col] = acc[r][c][i] + bias[col];
        }
      }
    }
}

} // namespace

extern "C" void kernel_launch(void* const* d_in, const int* in_sizes, int n_in,
                              void* d_out, int out_size, void* d_ws, size_t ws_size,
                              hipStream_t stream) {
  (void)in_sizes; (void)n_in; (void)out_size; (void)ws_size;
  const float* x[3] = {(const float*)d_in[0], (const float*)d_in[1], (const float*)d_in[2]};

  // ---- workspace layout ----
  char* p = (char*)d_ws;
  unsigned short* projfull = (unsigned short*)p;  p += (size_t)105000 * 256 * 2;
  unsigned short* nbft = (unsigned short*)p;      p += (size_t)70000 * 256 * 2;
  unsigned short* wcatbt = (unsigned short*)p;    p += (size_t)3 * 256 * 512 * 2;
  int* offs = (int*)p;                            p += (size_t)70004 * 4;
  int* counts = (int*)p;                          p += (size_t)70000 * 4;   // written by cnt2
  int* bcur = (int*)p;                            p += 160 * 4;             // zeroed
  int* ovcnt = (int*)p;                           p += 16;                  // zeroed
  int* part = (int*)p;                            p += 256;
  float* att_buf = (float*)p;                     p += (size_t)70000 * 4;
  unsigned int* csr_pay = (unsigned int*)p;       p += (size_t)1120000 * 4;
  // aliases into nbft (dead until gather_all):
  unsigned short* wshT = nbft;
  unsigned short* Wcbt = (unsigned short*)((char*)nbft + 393216);
  // record buffers alias projfull (dead until proj_mfma6 overwrites all rows):
  unsigned long long* rec2 = (unsigned long long*)projfull;            // 18 MB
  unsigned long long* ovbuf = rec2 + (size_t)NB2 * CAP2;               // 0.5 MB
  // bf16 copy of x lives in d_out (dead until final_mfma3 writes real output):
  unsigned short* xb = (unsigned short*)d_out;

  const int n_of[3] = {20000, 10000, 5000};
  const int nbt[3][2] = {{1, 2}, {0, 2}, {0, 1}};
  const int ebase[3][2] = {{3, 6}, {9, 12}, {15, 18}};
  const int nE3[3] = {320000, 160000, 80000};
  const size_t out_off[3] = {0, (size_t)20000 * 256, (size_t)30000 * 256};
  const int tstart[3] = {0, 15000, 40000};
  const int selfoff[3] = {70000, 90000, 100000};
  const int nboff[3] = {0, 40000, 60000};
  const int xboff[3] = {0, 20000, 30000};

  // ---- x -> bf16 ----
  cvt_x3<<<dim3(8750), 256, 0, stream>>>(x[0], x[1], x[2], xb);

  // ---- transpose+cvt: 3 wsh, 3 wcat ----
  Tc6 tc;
  for (int t = 0; t < 3; ++t) {
    tc.src[t] = (const float*)d_in[21 + t * 7 + 3];
    tc.dst[t] = wshT + (size_t)t * 256 * 256;
    tc.R[t] = 256;
    tc.src[3 + t] = (const float*)d_in[21 + t * 7 + 5];
    tc.dst[3 + t] = wcatbt + (size_t)t * 256 * 512;
    tc.R[3 + t] = 512;
  }
  transpose_cvt<<<dim3(8, 16, 6), 256, 0, stream>>>(tc);

  // ---- combined weights via MFMA ----
  Comb9 c9;
  for (int t = 0; t < 3; ++t) {
    int wb = 21 + t * 7;
    for (int j = 0; j < 3; ++j) {
      int combo = t * 3 + j;
      c9.A[combo] = wshT + (size_t)t * 256 * 256;
      c9.B[combo] = (const float*)d_in[wb + j];
      c9.C[combo] = Wcbt + (size_t)combo * 256 * 512;
    }
  }
  combine_mfma<<<dim3(4, 2, 9), 256, 0, stream>>>(c9);

  // ---- CSR build (LDS-staged two-level counting sort) ----
  Edges6 ep;
  const int cbase[6] = {0, 20000, 40000, 50000, 60000, 65000};
  for (int t = 0; t < 3; ++t)
    for (int r = 0; r < 2; ++r) {
      int rho = t * 2 + r, eb = ebase[t][r];
      ep.src[rho] = (const int*)d_in[eb];
      ep.dst[rho] = (const int*)d_in[eb + 1];
      ep.w[rho] = (const float*)d_in[eb + 2];
      ep.nE[rho] = nE3[t];
      ep.cbase[rho] = cbase[rho];
    }
  hipMemsetAsync(bcur, 0, 160 * 4 + 16, stream);
  bin1<<<dim3(313, 6), 256, 0, stream>>>(ep, bcur, ovcnt, rec2, ovbuf);
  cnt2<<<NB2, 256, 0, stream>>>(bcur, rec2, ovcnt, ovbuf, counts);
  scan1<<<35, 256, 0, stream>>>(counts, offs, part, 70000);
  scan2<<<1, 64, 0, stream>>>(part, 35, offs + 70000);
  scan3<<<274, 256, 0, stream>>>(offs, part, 70000);
  fine2<<<NB2, 512, 0, stream>>>(offs, bcur, rec2, ovcnt, ovbuf, csr_pay);

  // ---- projections: source-keyed, dense XCD-swizzled 1D grid ----
  Proj3 pj;
  {
    int cnum[3] = {0, 0, 0};
    for (int t = 0; t < 3; ++t) {
      int m0 = n_of[nbt[t][0]];
      for (int j = 0; j < 3; ++j) {
        int s = (j == 2) ? t : nbt[t][j];
        unsigned short* dst =
            (j == 0) ? projfull + (size_t)tstart[t] * 256
          : (j == 1) ? projfull + (size_t)(tstart[t] + m0) * 256
                     : projfull + (size_t)selfoff[t] * 256;
        int c = cnum[s]++;
        pj.Bt[s][c] = Wcbt + (size_t)(t * 3 + j) * 256 * 512;
        pj.C[s][c] = dst;
      }
    }
    for (int s = 0; s < 3; ++s) {
      pj.A[s] = xb + (size_t)xboff[s] * 512;
      pj.M[s] = n_of[s];
    }
  }
  proj_mfma6<<<dim3(PROJ_NWG), 256, 0, stream>>>(pj);

  // ---- all 6 gathers, one launch ----
  Gather6 gt;
  for (int t = 0; t < 3; ++t) {
    int m0 = n_of[nbt[t][0]];
    for (int r = 0; r < 2; ++r) {
      int rho = t * 2 + r;
      gt.proj[rho] = projfull + (size_t)(tstart[t] + (r ? m0 : 0)) * 256;
      gt.out[rho] = nbft + (size_t)(nboff[t] + r * n_of[t]) * 256;
      gt.cb[rho] = cbase[rho];
      gt.n[rho] = n_of[t];
    }
  }
  gather_all<<<dim3(5000, 6), 256, 0, stream>>>(gt, offs, csr_pay);

  // ---- attention (3 types) ----
  Att3 at;
  for (int t = 0; t < 3; ++t) {
    at.nb[t] = nbft + (size_t)nboff[t] * 256;
    at.self[t] = projfull + (size_t)selfoff[t] * 256;
    at.watt[t] = (const float*)d_in[21 + t * 7 + 4];
    at.att[t] = att_buf + nboff[t];
    at.n[t] = n_of[t];
  }
  e_att3<<<dim3(10000, 1, 3), 256, 0, stream>>>(at);

  // ---- final GEMM (3 types, BM=64, 64x64 wave tiles) ----
  Fin3 fn;
  for (int t = 0; t < 3; ++t) {
    fn.nb[t] = nbft + (size_t)nboff[t] * 256;
    fn.self[t] = projfull + (size_t)selfoff[t] * 256;
    fn.att[t] = att_buf + nboff[t];
    fn.Wt[t] = wcatbt + (size_t)t * 256 * 512;
    fn.bias[t] = (const float*)d_in[21 + t * 7 + 6];
    fn.out[t] = (float*)d_out + out_off[t];
    fn.M[t] = n_of[t];
  }
  final_mfma3<<<dim3(1, 313, 3), 256, 0, stream>>>(fn);
}

// Round 12
// 396.452 us; speedup vs baseline: 1.0697x; 1.0130x over previous
//
#include <hip/hip_runtime.h>

namespace {

typedef short s16x8 __attribute__((ext_vector_type(8)));
typedef float f32x4 __attribute__((ext_vector_type(4)));

__device__ __forceinline__ float bf2f(unsigned short u) {
  return __uint_as_float(((unsigned)u) << 16);
}
__device__ __forceinline__ unsigned short f2bf(float f) {
  unsigned u = __float_as_uint(f);
  u += 0x7fffu + ((u >> 16) & 1u);
  return (unsigned short)(u >> 16);
}

// async global->LDS, 16B per lane. LDS dest is wave-uniform base + lane*16.
typedef __attribute__((address_space(3))) unsigned int lds_u32;
typedef __attribute__((address_space(1))) const unsigned int glob_u32;
__device__ __forceinline__ void gl16(const void* g, void* l) {
  __builtin_amdgcn_global_load_lds((glob_u32*)g, (lds_u32*)l, 16, 0, 0);
}

// x (fp32) -> xb (bf16), 35000x512 total; xb lives in d_out (dead until final_mfma3).
__global__ __launch_bounds__(256) void cvt_x3(const float* __restrict__ x0,
                                              const float* __restrict__ x1,
                                              const float* __restrict__ x2,
                                              unsigned short* __restrict__ out) {
  size_t i = ((size_t)blockIdx.x * 256 + threadIdx.x) * 8;
  const float* src;
  size_t off;
  if (i < (size_t)20000 * 512) { src = x0; off = i; }
  else if (i < (size_t)30000 * 512) { src = x1; off = i - (size_t)20000 * 512; }
  else { src = x2; off = i - (size_t)30000 * 512; }
  float4 a = *(const float4*)(src + off);
  float4 b = *(const float4*)(src + off + 4);
  s16x8 v;
  v[0] = (short)f2bf(a.x); v[1] = (short)f2bf(a.y);
  v[2] = (short)f2bf(a.z); v[3] = (short)f2bf(a.w);
  v[4] = (short)f2bf(b.x); v[5] = (short)f2bf(b.y);
  v[6] = (short)f2bf(b.z); v[7] = (short)f2bf(b.w);
  *(s16x8*)(out + i) = v;
}

// fp32 [R][256] -> bf16 [256][R] (transposed). wsh: R=256, wcat: R=512.
struct Tc6 { const float* src[6]; unsigned short* dst[6]; int R[6]; };
__global__ __launch_bounds__(256) void transpose_cvt(Tc6 a) {
  int mat = blockIdx.z;
  int R = a.R[mat];
  int r0 = blockIdx.y * 32, c0 = blockIdx.x * 32;
  if (r0 >= R) return;
  const float* __restrict__ src = a.src[mat];
  unsigned short* __restrict__ dst = a.dst[mat];
  __shared__ float T[32][33];
  int tx = threadIdx.x & 31, ty = threadIdx.x >> 5;
  #pragma unroll
  for (int j = 0; j < 4; ++j) {
    int r = ty + j * 8;
    T[r][tx] = src[(size_t)(r0 + r) * 256 + c0 + tx];
  }
  __syncthreads();
  #pragma unroll
  for (int j = 0; j < 4; ++j) {
    int c = ty + j * 8;
    dst[(size_t)(c0 + c) * R + r0 + tx] = f2bf(T[tx][c]);
  }
}

// Wcbt[256x512] = wshT[256x256](bf16) @ W[512x256]^T(fp32, cvt on load)
struct Comb9 { const unsigned short* A[9]; const float* B[9]; unsigned short* C[9]; };
__global__ __launch_bounds__(256) void combine_mfma(Comb9 g) {
  int z = blockIdx.z;
  const unsigned short* __restrict__ A = g.A[z];
  const float* __restrict__ B = g.B[z];
  unsigned short* __restrict__ C = g.C[z];
  int row0 = blockIdx.y * 128;
  int col0 = blockIdx.x * 128;
  __shared__ unsigned short As[128 * 40];
  __shared__ unsigned short Bs[128 * 40];
  int tid = threadIdx.x, lane = tid & 63, w = tid >> 6;
  int quad = lane >> 4, m16 = lane & 15;
  f32x4 acc[2][8];
  #pragma unroll
  for (int r = 0; r < 2; ++r)
    #pragma unroll
    for (int c = 0; c < 8; ++c) acc[r][c] = (f32x4){0.f, 0.f, 0.f, 0.f};
  for (int k0 = 0; k0 < 256; k0 += 32) {
    #pragma unroll
    for (int i = 0; i < 2; ++i) {
      int ch = tid + i * 256;
      int m = ch >> 2, kk = (ch & 3) * 8;
      *(s16x8*)&As[m * 40 + kk] = *(const s16x8*)(A + (size_t)(row0 + m) * 256 + k0 + kk);
      const float4* bp = (const float4*)(B + (size_t)(col0 + m) * 256 + k0 + kk);
      float4 b0 = bp[0], b1 = bp[1];
      s16x8 bv;
      bv[0] = (short)f2bf(b0.x); bv[1] = (short)f2bf(b0.y);
      bv[2] = (short)f2bf(b0.z); bv[3] = (short)f2bf(b0.w);
      bv[4] = (short)f2bf(b1.x); bv[5] = (short)f2bf(b1.y);
      bv[6] = (short)f2bf(b1.z); bv[7] = (short)f2bf(b1.w);
      *(s16x8*)&Bs[m * 40 + kk] = bv;
    }
    __syncthreads();
    s16x8 af[2], bf[8];
    #pragma unroll
    for (int r = 0; r < 2; ++r)
      af[r] = *(const s16x8*)&As[(w * 32 + r * 16 + m16) * 40 + quad * 8];
    #pragma unroll
    for (int c = 0; c < 8; ++c)
      bf[c] = *(const s16x8*)&Bs[(c * 16 + m16) * 40 + quad * 8];
    #pragma unroll
    for (int r = 0; r < 2; ++r)
      #pragma unroll
      for (int c = 0; c < 8; ++c)
        acc[r][c] = __builtin_amdgcn_mfma_f32_16x16x32_bf16(af[r], bf[c], acc[r][c], 0, 0, 0);
    __syncthreads();
  }
  #pragma unroll
  for (int r = 0; r < 2; ++r)
    #pragma unroll
    for (int i = 0; i < 4; ++i) {
      int row = row0 + w * 32 + r * 16 + quad * 4 + i;
      #pragma unroll
      for (int c = 0; c < 8; ++c)
        C[(size_t)row * 512 + col0 + c * 16 + m16] = f2bf(acc[r][c][i]);
    }
}

// Projections: r7 block shape + XCD swizzle over a DENSE (hole-free) work space.
// s=0 tiles [0,942), s=1 [942,1416), s=2 [1416,1656). NWG=1656=8*207.
#define PROJ_NWG 1656
struct Proj3 { const unsigned short* A[3]; const unsigned short* Bt[3][3];
               unsigned short* C[3][3]; int M[3]; };
__global__ __launch_bounds__(256) void proj_mfma6(Proj3 g) {
  int orig = blockIdx.x;
  int wg = (orig & 7) * 207 + (orig >> 3);   // bijective: 1656 % 8 == 0
  int s, rem;
  if (wg < 942) { s = 0; rem = wg; }
  else if (wg < 1416) { s = 1; rem = wg - 942; }
  else { s = 2; rem = wg - 1416; }
  int by = rem / 6;
  int bx = rem - by * 6;
  int M = g.M[s];
  int row0 = by * 128;
  if (row0 >= M) return;                     // defensive (dense space: unreachable)
  int combo = bx >> 1;
  int col0 = (bx & 1) * 128;
  const unsigned short* __restrict__ A = g.A[s];
  const unsigned short* __restrict__ Bt = g.Bt[s][combo];   // 256 x 512
  unsigned short* __restrict__ C = g.C[s][combo];           // M x 256
  __shared__ unsigned short As[128 * 32];
  __shared__ unsigned short Bs[128 * 32];
  int tid = threadIdx.x, lane = tid & 63, w = tid >> 6;
  int quad = lane >> 4, m16 = lane & 15;
  int lr = lane >> 2;
  int lk = (((lane & 3) ^ (lr & 3) ^ ((lr >> 2) & 3))) * 8;
  int ar0 = row0 + w * 32 + lr;
  int ar1 = ar0 + 16;
  const unsigned short* a0p = A + (size_t)(ar0 < M ? ar0 : M - 1) * 512 + lk;
  const unsigned short* a1p = A + (size_t)(ar1 < M ? ar1 : M - 1) * 512 + lk;
  const unsigned short* b0p = Bt + (size_t)(col0 + w * 32 + lr) * 512 + lk;
  const unsigned short* b1p = b0p + (size_t)16 * 512;
  unsigned short* as0 = &As[w * 1024];
  unsigned short* as1 = &As[w * 1024 + 512];
  unsigned short* bs0 = &Bs[w * 1024];
  unsigned short* bs1 = &Bs[w * 1024 + 512];
  int wr = (w & 1) * 64, wc = (w >> 1) * 64;
  int sw = ((quad ^ (m16 & 3) ^ ((m16 >> 2) & 3))) * 8;
  f32x4 acc[4][4];
  #pragma unroll
  for (int r = 0; r < 4; ++r)
    #pragma unroll
    for (int c = 0; c < 4; ++c) acc[r][c] = (f32x4){0.f, 0.f, 0.f, 0.f};
  for (int k0 = 0; k0 < 512; k0 += 32) {
    gl16(a0p + k0, as0);
    gl16(a1p + k0, as1);
    gl16(b0p + k0, bs0);
    gl16(b1p + k0, bs1);
    __syncthreads();
    s16x8 af[4], bf[4];
    #pragma unroll
    for (int r = 0; r < 4; ++r)
      af[r] = *(const s16x8*)&As[(wr + r * 16 + m16) * 32 + sw];
    #pragma unroll
    for (int c = 0; c < 4; ++c)
      bf[c] = *(const s16x8*)&Bs[(wc + c * 16 + m16) * 32 + sw];
    #pragma unroll
    for (int r = 0; r < 4; ++r)
      #pragma unroll
      for (int c = 0; c < 4; ++c)
        acc[r][c] = __builtin_amdgcn_mfma_f32_16x16x32_bf16(af[r], bf[c], acc[r][c], 0, 0, 0);
    __syncthreads();
  }
  #pragma unroll
  for (int r = 0; r < 4; ++r)
    #pragma unroll
    for (int i = 0; i < 4; ++i) {
      int row = row0 + wr + r * 16 + quad * 4 + i;
      if (row < M) {
        #pragma unroll
        for (int c = 0; c < 4; ++c)
          C[(size_t)row * 256 + col0 + wc + c * 16 + m16] = f2bf(acc[r][c][i]);
      }
    }
}

struct Edges6 { const int* src[6]; const int* dst[6]; const float* w[6]; int nE[6]; int cbase[6]; };

// ---- CSR build: LDS-staged two-level counting sort ----
#define BSH 9
#define NB2 137            // ceil(70000 / 512)
#define CAP2 16384         // padded mean ~12.3K; huge margin + overflow path
#define NOV 65536
#define CH 1024
#define NPAY 1120000

__global__ __launch_bounds__(256) void bin1(Edges6 ep,
                                            int* __restrict__ bcur, int* __restrict__ ovcnt,
                                            unsigned long long* __restrict__ rec2,
                                            unsigned long long* __restrict__ ovbuf) {
  int rho = blockIdx.y;
  int nE = ep.nE[rho];
  int chunk = blockIdx.x * CH;
  if (chunk >= nE) return;
  int n = nE - chunk; if (n > CH) n = CH;
  const int* __restrict__ srcp = ep.src[rho];
  const int* __restrict__ dstp = ep.dst[rho];
  const float* __restrict__ wp = ep.w[rho];
  int cb = ep.cbase[rho];
  __shared__ int h[256], excl[256], lcur[256], gbase[256], rsv[256];
  __shared__ int wsum[4];
  __shared__ unsigned long long stage[CH];
  int t = threadIdx.x;
  h[t] = 0;
  gbase[t] = 0;
  __syncthreads();
  int gd[4]; unsigned pv[4];
  #pragma unroll
  for (int j = 0; j < 4; ++j) {
    int idx = t + j * 256;
    gd[j] = -1;
    if (idx < n) {
      int e = chunk + idx;
      int g = cb + dstp[e];
      if (g < 0) g = 0;
      if (g > 69999) g = 69999;       // defensive (inputs guarantee in-range)
      gd[j] = g;
      pv[j] = (((unsigned)f2bf(wp[e])) << 16) | ((unsigned)srcp[e] & 0x7fffu);
      atomicAdd(&h[g >> BSH], 1);
    }
  }
  __syncthreads();
  int hv = h[t];
  int lane = t & 63, wv = t >> 6;
  int v = hv;
  #pragma unroll
  for (int off = 1; off < 64; off <<= 1) {
    int u = __shfl_up(v, off, 64);
    if (lane >= off) v += u;
  }
  if (lane == 63) wsum[wv] = v;
  __syncthreads();
  int add = 0;
  #pragma unroll
  for (int k = 0; k < 3; ++k)
    if (k < wv) add += wsum[k];
  v += add;
  int ex = v - hv;
  excl[t] = ex;
  lcur[t] = ex;
  int rv = 0;
  if (t < NB2 && hv > 0) {
    rv = (hv + 7) & ~7;               // 64B-aligned reservation
    gbase[t] = atomicAdd(&bcur[t], rv);
  }
  rsv[t] = rv;
  __syncthreads();
  #pragma unroll
  for (int j = 0; j < 4; ++j) {
    if (gd[j] >= 0) {
      int b = gd[j] >> BSH;
      int slot = atomicAdd(&lcur[b], 1);
      if (slot >= 0 && slot < CH)
        stage[slot] = ((unsigned long long)(unsigned)gd[j] << 32) | pv[j];
    }
  }
  __syncthreads();
  for (int s = t; s < n; s += 256) {
    int lo = 0, hi = NB2 - 1;
    while (lo < hi) {
      int mid = (lo + hi + 1) >> 1;
      if (excl[mid] <= s) lo = mid; else hi = mid - 1;
    }
    int b = lo;
    int gp = gbase[b] + (s - excl[b]);
    if (gp >= 0 && gp < CAP2) rec2[(size_t)b * CAP2 + gp] = stage[s];
    else { int op = atomicAdd(ovcnt, 1); ovbuf[op & (NOV - 1)] = stage[s]; }
  }
  for (int b = t; b < NB2; b += 256) {
    int hvb = h[b], rvb = rsv[b], gb = gbase[b];
    for (int k = hvb; k < rvb; ++k) {
      int gp = gb + k;
      if (gp >= 0 && gp < CAP2) rec2[(size_t)b * CAP2 + gp] = 0xFFFFFFFFFFFFFFFFull;
    }
  }
}

__global__ __launch_bounds__(256) void cnt2(const int* __restrict__ bcur,
                                            const unsigned long long* __restrict__ rec2,
                                            const int* __restrict__ ovcnt,
                                            const unsigned long long* __restrict__ ovbuf,
                                            int* __restrict__ counts) {
  int b = blockIdx.x;
  __shared__ int c[512];
  int t = threadIdx.x;
  c[t] = 0; c[t + 256] = 0;
  __syncthreads();
  int nrec = bcur[b];
  nrec = nrec < CAP2 ? nrec : CAP2;
  const unsigned long long* rp = rec2 + (size_t)b * CAP2;
  for (int i = t; i < nrec; i += 256) {
    int gd = (int)(rp[i] >> 32);
    if (gd >= 0) atomicAdd(&c[gd & 511], 1);
  }
  int ovn = *ovcnt;
  ovn = ovn < NOV ? ovn : NOV;
  for (int i = t; i < ovn; i += 256) {
    int gd = (int)(ovbuf[i] >> 32);
    if (gd >= 0 && (gd >> BSH) == b) atomicAdd(&c[gd & 511], 1);
  }
  __syncthreads();
  int g0 = (b << BSH) + t;
  if (g0 < 70000) counts[g0] = c[t];
  int g1 = g0 + 256;
  if (g1 < 70000) counts[g1] = c[t + 256];
}

__global__ __launch_bounds__(256) void scan1(const int* __restrict__ cnt, int* __restrict__ out,
                                             int* __restrict__ part, int len) {
  __shared__ int sh[256];
  int base = blockIdx.x * 2048 + threadIdx.x * 8;
  int v[8];
  int s = 0;
  #pragma unroll
  for (int j = 0; j < 8; ++j) {
    int i = base + j;
    int x = (i < len) ? cnt[i] : 0;
    v[j] = s;
    s += x;
  }
  sh[threadIdx.x] = s;
  __syncthreads();
  for (int off = 1; off < 256; off <<= 1) {
    int t = (threadIdx.x >= off) ? sh[threadIdx.x - off] : 0;
    __syncthreads();
    sh[threadIdx.x] += t;
    __syncthreads();
  }
  int texcl = sh[threadIdx.x] - s;
  #pragma unroll
  for (int j = 0; j < 8; ++j) {
    int i = base + j;
    if (i < len) out[i] = texcl + v[j];
  }
  if (threadIdx.x == 255) part[blockIdx.x] = sh[255];
}

__global__ void scan2(int* __restrict__ part, int nb, int* __restrict__ total_out) {
  __shared__ int sh[64];
  int t = threadIdx.x;
  int v = (t < nb) ? part[t] : 0;
  sh[t] = v;
  __syncthreads();
  for (int off = 1; off < 64; off <<= 1) {
    int x = (t >= off) ? sh[t - off] : 0;
    __syncthreads();
    sh[t] += x;
    __syncthreads();
  }
  if (t < nb) part[t] = sh[t] - v;
  if (t == 63) *total_out = sh[63];
}

__global__ __launch_bounds__(256) void scan3(int* __restrict__ offs,
                                             const int* __restrict__ part, int len) {
  int i = blockIdx.x * 256 + threadIdx.x;
  if (i >= len) return;
  offs[i] += part[i >> 11];
}

__global__ __launch_bounds__(512) void fine2(const int* __restrict__ offs,
                                             const int* __restrict__ bcur,
                                             const unsigned long long* __restrict__ rec2,
                                             const int* __restrict__ ovcnt,
                                             const unsigned long long* __restrict__ ovbuf,
                                             unsigned int* __restrict__ pay) {
  int b = blockIdx.x;
  __shared__ int cur[512];
  int t = threadIdx.x;
  {
    int gd = (b << BSH) + t;
    cur[t] = (gd < 70000) ? offs[gd] : 0;
  }
  __syncthreads();
  int nrec = bcur[b];
  nrec = nrec < CAP2 ? nrec : CAP2;
  const unsigned long long* rp = rec2 + (size_t)b * CAP2;
  for (int i = t; i < nrec; i += 512) {
    unsigned long long r = rp[i];
    int gd = (int)(r >> 32);
    if (gd < 0) continue;             // sentinel pad
    int pos = atomicAdd(&cur[gd & 511], 1);
    if (pos >= 0 && pos < NPAY) pay[pos] = (unsigned)r;
  }
  int ovn = *ovcnt;
  ovn = ovn < NOV ? ovn : NOV;
  for (int i = t; i < ovn; i += 512) {
    unsigned long long r = ovbuf[i];
    int gd = (int)(r >> 32);
    if (gd >= 0 && (gd >> BSH) == b) {
      int pos = atomicAdd(&cur[gd & 511], 1);
      if (pos >= 0 && pos < NPAY) pay[pos] = (unsigned)r;
    }
  }
}

// all 6 relations; dense 1D grid, rel-major (blocks per rel: 5000,5000,2500,
// 2500,1250,1250 = 17500 = 8*2187+4) + m204 bijective XCD swizzle: each XCD
// gets a contiguous dst-range of ~one relation -> its L2 holds ONE src panel
// instead of all six (r11: FETCH 115.6MB = 3.2x the 35.8MB unique -> panel
// replication across the 8 L2s). Per-dst expected degree is 16 for every
// relation, so contiguous chunks stay load-balanced. 8 edges in flight per
// wave (4 per half-wave) for deeper memory-level parallelism.
#define GAT_NWG 17500
struct Gather6 { const unsigned short* proj[6]; unsigned short* out[6]; int cb[6]; int n[6]; };
__global__ __launch_bounds__(256) void gather_all(Gather6 g, const int* __restrict__ offs,
                                                  const unsigned int* __restrict__ pay) {
  int orig = blockIdx.x;
  // bijective XCD remap: q=2187, r=4  (17500 = 8*2187 + 4)
  int xcd = orig & 7, idx = orig >> 3;
  int wg = (xcd < 4 ? xcd * 2188 : 4 * 2188 + (xcd - 4) * 2187) + idx;
  int rho, base;
  if (wg < 5000) { rho = 0; base = 0; }
  else if (wg < 10000) { rho = 1; base = 5000; }
  else if (wg < 12500) { rho = 2; base = 10000; }
  else if (wg < 15000) { rho = 3; base = 12500; }
  else if (wg < 16250) { rho = 4; base = 15000; }
  else { rho = 5; base = 16250; }
  int n = g.n[rho];
  int d = (wg - base) * 4 + (threadIdx.x >> 6);
  if (d >= n) return;                 // defensive (dense: n % 4 == 0 for all rels)
  int lane = threadIdx.x & 63, half = lane >> 5, l32 = lane & 31;
  const unsigned short* __restrict__ proj = g.proj[rho];
  const int* of = offs + g.cb[rho];
  int s0 = of[d], s1 = of[d + 1];
  float acc[8] = {};
  int e = s0 + half;
  // 8 edges in flight per wave (4 per half-wave), 4 independent pay->row chains
  for (; e + 6 < s1; e += 8) {
    unsigned int u0 = pay[e], u1 = pay[e + 2], u2 = pay[e + 4], u3 = pay[e + 6];
    float wt0 = bf2f((unsigned short)(u0 >> 16));
    float wt1 = bf2f((unsigned short)(u1 >> 16));
    float wt2 = bf2f((unsigned short)(u2 >> 16));
    float wt3 = bf2f((unsigned short)(u3 >> 16));
    s16x8 v0 = *(const s16x8*)(proj + (size_t)(u0 & 0xffffu) * 256 + l32 * 8);
    s16x8 v1 = *(const s16x8*)(proj + (size_t)(u1 & 0xffffu) * 256 + l32 * 8);
    s16x8 v2 = *(const s16x8*)(proj + (size_t)(u2 & 0xffffu) * 256 + l32 * 8);
    s16x8 v3 = *(const s16x8*)(proj + (size_t)(u3 & 0xffffu) * 256 + l32 * 8);
    #pragma unroll
    for (int j = 0; j < 8; ++j) {
      acc[j] = fmaf(bf2f((unsigned short)v0[j]), wt0, acc[j]);
      acc[j] = fmaf(bf2f((unsigned short)v1[j]), wt1, acc[j]);
      acc[j] = fmaf(bf2f((unsigned short)v2[j]), wt2, acc[j]);
      acc[j] = fmaf(bf2f((unsigned short)v3[j]), wt3, acc[j]);
    }
  }
  for (; e < s1; e += 2) {
    unsigned int u = pay[e];
    float wt = bf2f((unsigned short)(u >> 16));
    s16x8 v = *(const s16x8*)(proj + (size_t)(u & 0xffffu) * 256 + l32 * 8);
    #pragma unroll
    for (int j = 0; j < 8; ++j) acc[j] = fmaf(bf2f((unsigned short)v[j]), wt, acc[j]);
  }
  #pragma unroll
  for (int j = 0; j < 8; ++j) acc[j] += __shfl(acc[j], lane ^ 32, 64);
  if (half == 0) {
    s16x8 o;
    #pragma unroll
    for (int j = 0; j < 8; ++j) o[j] = (short)f2bf(acc[j]);
    *(s16x8*)(g.out[rho] + (size_t)d * 256 + l32 * 8) = o;
  }
}

// all 3 types: scores + FAITHFUL reshape(n,2) softmax over adjacent e-pairs
struct Att3 { const unsigned short* nb[3]; const unsigned short* self[3];
              const float* watt[3]; float* att[3]; int n[3]; };
__global__ __launch_bounds__(256) void e_att3(Att3 g) {
  int z = blockIdx.z;
  int n = g.n[z];
  int wv = threadIdx.x >> 6;
  int idx = blockIdx.x * 4 + wv;
  int lane = threadIdx.x & 63;
  __shared__ float ev[4];
  float sum = 0.f;
  if (idx < 2 * n) {
    int i = idx < n ? idx : idx - n;
    ushort4 v  = *(const ushort4*)(g.nb[z] + (size_t)idx * 256 + (lane << 2));
    ushort4 sv = *(const ushort4*)(g.self[z] + (size_t)i * 256 + (lane << 2));
    float4 wa = *(const float4*)(g.watt[z] + (lane << 2));
    float4 wb = *(const float4*)(g.watt[z] + 256 + (lane << 2));
    sum = bf2f(v.x) * wa.x + bf2f(v.y) * wa.y + bf2f(v.z) * wa.z + bf2f(v.w) * wa.w +
          bf2f(sv.x) * wb.x + bf2f(sv.y) * wb.y + bf2f(sv.z) * wb.z + bf2f(sv.w) * wb.w;
    #pragma unroll
    for (int off = 32; off > 0; off >>= 1) sum += __shfl_down(sum, off, 64);
  }
  if (lane == 0) ev[wv] = sum;
  __syncthreads();
  if (threadIdx.x < 2) {
    int base = blockIdx.x * 4 + threadIdx.x * 2;
    if (base < 2 * n) {
      float f0 = ev[threadIdx.x * 2], f1 = ev[threadIdx.x * 2 + 1];
      f0 = f0 > 0.f ? f0 : 0.01f * f0;
      f1 = f1 > 0.f ? f1 : 0.01f * f1;
      float m = fmaxf(f0, f1);
      float a = expf(f0 - m), b = expf(f1 - m);
      float inv = 1.f / (a + b);
      g.att[z][base] = a * inv;
      g.att[z][base + 1] = b * inv;
    }
  }
}

// all 3 types, BM=64/BN=256, 64x64 wave tiles, pipelined staging.
struct Fin3 { const unsigned short* nb[3]; const unsigned short* self[3]; const float* att[3];
              const unsigned short* Wt[3]; const float* bias[3]; float* out[3]; int M[3]; };
__global__ __launch_bounds__(256, 3) void final_mfma3(Fin3 g) {
  int z = blockIdx.z;
  int M = g.M[z];
  int row0 = blockIdx.y * 64;
  if (row0 >= M) return;
  const unsigned short* __restrict__ nbft = g.nb[z];
  const unsigned short* __restrict__ selfb = g.self[z];
  const float* __restrict__ att = g.att[z];
  const unsigned short* __restrict__ Wt = g.Wt[z];
  __shared__ unsigned short As[64 * 40];
  __shared__ unsigned short Bs[256 * 40];
  int tid = threadIdx.x, lane = tid & 63, w = tid >> 6;
  int quad = lane >> 4, m16 = lane & 15;
  int am = tid >> 2, akk = (tid & 3) * 8;
  int gr = row0 + am;
  float a0 = 0.f, a1 = 0.f;
  if (gr < M) { a0 = att[2 * gr]; a1 = att[2 * gr + 1]; }
  f32x4 acc[4][4];
  #pragma unroll
  for (int r = 0; r < 4; ++r)
    #pragma unroll
    for (int c = 0; c < 4; ++c) acc[r][c] = (f32x4){0.f, 0.f, 0.f, 0.f};

  s16x8 pu0 = {}, pu1 = {};
  s16x8 pb[4];

  auto loadA = [&](int k0) {
    int kg = k0 + akk;
    if (gr < M) {
      if (kg < 256) {
        pu0 = *(const s16x8*)(nbft + (size_t)gr * 256 + kg);
        pu1 = *(const s16x8*)(nbft + ((size_t)M + gr) * 256 + kg);
      } else {
        pu0 = *(const s16x8*)(selfb + (size_t)gr * 256 + (kg - 256));
      }
    }
  };
  auto loadB = [&](int k0) {
    #pragma unroll
    for (int i = 0; i < 4; ++i) {
      int ch = tid + i * 256;
      int m = ch >> 2, kk = (ch & 3) * 8;
      pb[i] = *(const s16x8*)(Wt + (size_t)m * 512 + k0 + kk);
    }
  };
  auto storeLDS = [&](int k0) {
    int kg = k0 + akk;
    s16x8 v = {};
    if (gr < M) {
      if (kg < 256) {
        #pragma unroll
        for (int j = 0; j < 8; ++j)
          v[j] = (short)f2bf(fmaf(a0, bf2f((unsigned short)pu0[j]),
                                  a1 * bf2f((unsigned short)pu1[j])));
      } else {
        v = pu0;
      }
    }
    *(s16x8*)&As[am * 40 + akk] = v;
    #pragma unroll
    for (int i = 0; i < 4; ++i) {
      int ch = tid + i * 256;
      int m = ch >> 2, kk = (ch & 3) * 8;
      *(s16x8*)&Bs[m * 40 + kk] = pb[i];
    }
  };

  loadA(0); loadB(0); storeLDS(0);
  __syncthreads();
  for (int k0 = 0; k0 < 512; k0 += 32) {
    int kn = k0 + 32;
    if (kn < 512) { loadA(kn); loadB(kn); }
    s16x8 af[4], bf[4];
    #pragma unroll
    for (int r = 0; r < 4; ++r)
      af[r] = *(const s16x8*)&As[(r * 16 + m16) * 40 + quad * 8];
    #pragma unroll
    for (int c = 0; c < 4; ++c)
      bf[c] = *(const s16x8*)&Bs[(w * 64 + c * 16 + m16) * 40 + quad * 8];
    #pragma unroll
    for (int r = 0; r < 4; ++r)
      #pragma unroll
      for (int c = 0; c < 4; ++c)
        acc[r][c] = __builtin_amdgcn_mfma_f32_16x16x32_bf16(af[r], bf[c], acc[r][c], 0, 0, 0);
    __syncthreads();
    if (kn < 512) {
      storeLDS(kn);
      __syncthreads();
    }
  }
  const float* __restrict__ bias = g.bias[z];
  float* __restrict__ out = g.out[z];
  #pragma unroll
  for (int r = 0; r < 4; ++r)
    #pragma unroll
    for (int i = 0; i < 4; ++i) {
      int row = row0 + r * 16 + quad * 4 + i;
      if (row < M) {
        #pragma unroll
        for (int c = 0; c < 4; ++c) {
          int col = w * 64 + c * 16 + m16;
          out[(size_t)row * 256 + col] = acc[r][c][i] + bias[col];
        }
      }
    }
}

} // namespace

extern "C" void kernel_launch(void* const* d_in, const int* in_sizes, int n_in,
                              void* d_out, int out_size, void* d_ws, size_t ws_size,
                              hipStream_t stream) {
  (void)in_sizes; (void)n_in; (void)out_size; (void)ws_size;
  const float* x[3] = {(const float*)d_in[0], (const float*)d_in[1], (const float*)d_in[2]};

  // ---- workspace layout ----
  char* p = (char*)d_ws;
  unsigned short* projfull = (unsigned short*)p;  p += (size_t)105000 * 256 * 2;
  unsigned short* nbft = (unsigned short*)p;      p += (size_t)70000 * 256 * 2;
  unsigned short* wcatbt = (unsigned short*)p;    p += (size_t)3 * 256 * 512 * 2;
  int* offs = (int*)p;                            p += (size_t)70004 * 4;
  int* counts = (int*)p;                          p += (size_t)70000 * 4;   // written by cnt2
  int* bcur = (int*)p;                            p += 160 * 4;             // zeroed
  int* ovcnt = (int*)p;                           p += 16;                  // zeroed
  int* part = (int*)p;                            p += 256;
  float* att_buf = (float*)p;                     p += (size_t)70000 * 4;
  unsigned int* csr_pay = (unsigned int*)p;       p += (size_t)1120000 * 4;
  // aliases into nbft (dead until gather_all):
  unsigned short* wshT = nbft;
  unsigned short* Wcbt = (unsigned short*)((char*)nbft + 393216);
  // record buffers alias projfull (dead until proj_mfma6 overwrites all rows):
  unsigned long long* rec2 = (unsigned long long*)projfull;            // 18 MB
  unsigned long long* ovbuf = rec2 + (size_t)NB2 * CAP2;               // 0.5 MB
  // bf16 copy of x lives in d_out (dead until final_mfma3 writes real output):
  unsigned short* xb = (unsigned short*)d_out;

  const int n_of[3] = {20000, 10000, 5000};
  const int nbt[3][2] = {{1, 2}, {0, 2}, {0, 1}};
  const int ebase[3][2] = {{3, 6}, {9, 12}, {15, 18}};
  const int nE3[3] = {320000, 160000, 80000};
  const size_t out_off[3] = {0, (size_t)20000 * 256, (size_t)30000 * 256};
  const int tstart[3] = {0, 15000, 40000};
  const int selfoff[3] = {70000, 90000, 100000};
  const int nboff[3] = {0, 40000, 60000};
  const int xboff[3] = {0, 20000, 30000};

  // ---- x -> bf16 ----
  cvt_x3<<<dim3(8750), 256, 0, stream>>>(x[0], x[1], x[2], xb);

  // ---- transpose+cvt: 3 wsh, 3 wcat ----
  Tc6 tc;
  for (int t = 0; t < 3; ++t) {
    tc.src[t] = (const float*)d_in[21 + t * 7 + 3];
    tc.dst[t] = wshT + (size_t)t * 256 * 256;
    tc.R[t] = 256;
    tc.src[3 + t] = (const float*)d_in[21 + t * 7 + 5];
    tc.dst[3 + t] = wcatbt + (size_t)t * 256 * 512;
    tc.R[3 + t] = 512;
  }
  transpose_cvt<<<dim3(8, 16, 6), 256, 0, stream>>>(tc);

  // ---- combined weights via MFMA ----
  Comb9 c9;
  for (int t = 0; t < 3; ++t) {
    int wb = 21 + t * 7;
    for (int j = 0; j < 3; ++j) {
      int combo = t * 3 + j;
      c9.A[combo] = wshT + (size_t)t * 256 * 256;
      c9.B[combo] = (const float*)d_in[wb + j];
      c9.C[combo] = Wcbt + (size_t)combo * 256 * 512;
    }
  }
  combine_mfma<<<dim3(4, 2, 9), 256, 0, stream>>>(c9);

  // ---- CSR build (LDS-staged two-level counting sort) ----
  Edges6 ep;
  const int cbase[6] = {0, 20000, 40000, 50000, 60000, 65000};
  for (int t = 0; t < 3; ++t)
    for (int r = 0; r < 2; ++r) {
      int rho = t * 2 + r, eb = ebase[t][r];
      ep.src[rho] = (const int*)d_in[eb];
      ep.dst[rho] = (const int*)d_in[eb + 1];
      ep.w[rho] = (const float*)d_in[eb + 2];
      ep.nE[rho] = nE3[t];
      ep.cbase[rho] = cbase[rho];
    }
  hipMemsetAsync(bcur, 0, 160 * 4 + 16, stream);
  bin1<<<dim3(313, 6), 256, 0, stream>>>(ep, bcur, ovcnt, rec2, ovbuf);
  cnt2<<<NB2, 256, 0, stream>>>(bcur, rec2, ovcnt, ovbuf, counts);
  scan1<<<35, 256, 0, stream>>>(counts, offs, part, 70000);
  scan2<<<1, 64, 0, stream>>>(part, 35, offs + 70000);
  scan3<<<274, 256, 0, stream>>>(offs, part, 70000);
  fine2<<<NB2, 512, 0, stream>>>(offs, bcur, rec2, ovcnt, ovbuf, csr_pay);

  // ---- projections: source-keyed, dense XCD-swizzled 1D grid ----
  Proj3 pj;
  {
    int cnum[3] = {0, 0, 0};
    for (int t = 0; t < 3; ++t) {
      int m0 = n_of[nbt[t][0]];
      for (int j = 0; j < 3; ++j) {
        int s = (j == 2) ? t : nbt[t][j];
        unsigned short* dst =
            (j == 0) ? projfull + (size_t)tstart[t] * 256
          : (j == 1) ? projfull + (size_t)(tstart[t] + m0) * 256
                     : projfull + (size_t)selfoff[t] * 256;
        int c = cnum[s]++;
        pj.Bt[s][c] = Wcbt + (size_t)(t * 3 + j) * 256 * 512;
        pj.C[s][c] = dst;
      }
    }
    for (int s = 0; s < 3; ++s) {
      pj.A[s] = xb + (size_t)xboff[s] * 512;
      pj.M[s] = n_of[s];
    }
  }
  proj_mfma6<<<dim3(PROJ_NWG), 256, 0, stream>>>(pj);

  // ---- all 6 gathers: dense rel-major 1D grid + XCD swizzle ----
  Gather6 gt;
  for (int t = 0; t < 3; ++t) {
    int m0 = n_of[nbt[t][0]];
    for (int r = 0; r < 2; ++r) {
      int rho = t * 2 + r;
      gt.proj[rho] = projfull + (size_t)(tstart[t] + (r ? m0 : 0)) * 256;
      gt.out[rho] = nbft + (size_t)(nboff[t] + r * n_of[t]) * 256;
      gt.cb[rho] = cbase[rho];
      gt.n[rho] = n_of[t];
    }
  }
  gather_all<<<dim3(GAT_NWG), 256, 0, stream>>>(gt, offs, csr_pay);

  // ---- attention (3 types) ----
  Att3 at;
  for (int t = 0; t < 3; ++t) {
    at.nb[t] = nbft + (size_t)nboff[t] * 256;
    at.self[t] = projfull + (size_t)selfoff[t] * 256;
    at.watt[t] = (const float*)d_in[21 + t * 7 + 4];
    at.att[t] = att_buf + nboff[t];
    at.n[t] = n_of[t];
  }
  e_att3<<<dim3(10000, 1, 3), 256, 0, stream>>>(at);

  // ---- final GEMM (3 types, BM=64, 64x64 wave tiles) ----
  Fin3 fn;
  for (int t = 0; t < 3; ++t) {
    fn.nb[t] = nbft + (size_t)nboff[t] * 256;
    fn.self[t] = projfull + (size_t)selfoff[t] * 256;
    fn.att[t] = att_buf + nboff[t];
    fn.Wt[t] = wcatbt + (size_t)t * 256 * 512;
    fn.bias[t] = (const float*)d_in[21 + t * 7 + 6];
    fn.out[t] = (float*)d_out + out_off[t];
    fn.M[t] = n_of[t];
  }
  final_mfma3<<<dim3(1, 313, 3), 256, 0, stream>>>(fn);
}

// Round 14
// 393.665 us; speedup vs baseline: 1.0773x; 1.0071x over previous
//
#include <hip/hip_runtime.h>

namespace {

typedef short s16x8 __attribute__((ext_vector_type(8)));
typedef float f32x4 __attribute__((ext_vector_type(4)));

__device__ __forceinline__ float bf2f(unsigned short u) {
  return __uint_as_float(((unsigned)u) << 16);
}
__device__ __forceinline__ unsigned short f2bf(float f) {
  unsigned u = __float_as_uint(f);
  u += 0x7fffu + ((u >> 16) & 1u);
  return (unsigned short)(u >> 16);
}

// async global->LDS, 16B per lane. LDS dest is wave-uniform base + lane*16.
typedef __attribute__((address_space(3))) unsigned int lds_u32;
typedef __attribute__((address_space(1))) const unsigned int glob_u32;
__device__ __forceinline__ void gl16(const void* g, void* l) {
  __builtin_amdgcn_global_load_lds((glob_u32*)g, (lds_u32*)l, 16, 0, 0);
}

// x (fp32) -> xb (bf16), 35000x512 total; xb lives in d_out (dead until final_mfma3).
__global__ __launch_bounds__(256) void cvt_x3(const float* __restrict__ x0,
                                              const float* __restrict__ x1,
                                              const float* __restrict__ x2,
                                              unsigned short* __restrict__ out) {
  size_t i = ((size_t)blockIdx.x * 256 + threadIdx.x) * 8;
  const float* src;
  size_t off;
  if (i < (size_t)20000 * 512) { src = x0; off = i; }
  else if (i < (size_t)30000 * 512) { src = x1; off = i - (size_t)20000 * 512; }
  else { src = x2; off = i - (size_t)30000 * 512; }
  float4 a = *(const float4*)(src + off);
  float4 b = *(const float4*)(src + off + 4);
  s16x8 v;
  v[0] = (short)f2bf(a.x); v[1] = (short)f2bf(a.y);
  v[2] = (short)f2bf(a.z); v[3] = (short)f2bf(a.w);
  v[4] = (short)f2bf(b.x); v[5] = (short)f2bf(b.y);
  v[6] = (short)f2bf(b.z); v[7] = (short)f2bf(b.w);
  *(s16x8*)(out + i) = v;
}

// fp32 [R][256] -> bf16 [256][R] (transposed). wsh: R=256, wcat: R=512.
struct Tc6 { const float* src[6]; unsigned short* dst[6]; int R[6]; };
__global__ __launch_bounds__(256) void transpose_cvt(Tc6 a) {
  int mat = blockIdx.z;
  int R = a.R[mat];
  int r0 = blockIdx.y * 32, c0 = blockIdx.x * 32;
  if (r0 >= R) return;
  const float* __restrict__ src = a.src[mat];
  unsigned short* __restrict__ dst = a.dst[mat];
  __shared__ float T[32][33];
  int tx = threadIdx.x & 31, ty = threadIdx.x >> 5;
  #pragma unroll
  for (int j = 0; j < 4; ++j) {
    int r = ty + j * 8;
    T[r][tx] = src[(size_t)(r0 + r) * 256 + c0 + tx];
  }
  __syncthreads();
  #pragma unroll
  for (int j = 0; j < 4; ++j) {
    int c = ty + j * 8;
    dst[(size_t)(c0 + c) * R + r0 + tx] = f2bf(T[tx][c]);
  }
}

// Wcbt[256x512] = wshT[256x256](bf16) @ W[512x256]^T(fp32, cvt on load)
struct Comb9 { const unsigned short* A[9]; const float* B[9]; unsigned short* C[9]; };
__global__ __launch_bounds__(256) void combine_mfma(Comb9 g) {
  int z = blockIdx.z;
  const unsigned short* __restrict__ A = g.A[z];
  const float* __restrict__ B = g.B[z];
  unsigned short* __restrict__ C = g.C[z];
  int row0 = blockIdx.y * 128;
  int col0 = blockIdx.x * 128;
  __shared__ unsigned short As[128 * 40];
  __shared__ unsigned short Bs[128 * 40];
  int tid = threadIdx.x, lane = tid & 63, w = tid >> 6;
  int quad = lane >> 4, m16 = lane & 15;
  f32x4 acc[2][8];
  #pragma unroll
  for (int r = 0; r < 2; ++r)
    #pragma unroll
    for (int c = 0; c < 8; ++c) acc[r][c] = (f32x4){0.f, 0.f, 0.f, 0.f};
  for (int k0 = 0; k0 < 256; k0 += 32) {
    #pragma unroll
    for (int i = 0; i < 2; ++i) {
      int ch = tid + i * 256;
      int m = ch >> 2, kk = (ch & 3) * 8;
      *(s16x8*)&As[m * 40 + kk] = *(const s16x8*)(A + (size_t)(row0 + m) * 256 + k0 + kk);
      const float4* bp = (const float4*)(B + (size_t)(col0 + m) * 256 + k0 + kk);
      float4 b0 = bp[0], b1 = bp[1];
      s16x8 bv;
      bv[0] = (short)f2bf(b0.x); bv[1] = (short)f2bf(b0.y);
      bv[2] = (short)f2bf(b0.z); bv[3] = (short)f2bf(b0.w);
      bv[4] = (short)f2bf(b1.x); bv[5] = (short)f2bf(b1.y);
      bv[6] = (short)f2bf(b1.z); bv[7] = (short)f2bf(b1.w);
      *(s16x8*)&Bs[m * 40 + kk] = bv;
    }
    __syncthreads();
    s16x8 af[2], bf[8];
    #pragma unroll
    for (int r = 0; r < 2; ++r)
      af[r] = *(const s16x8*)&As[(w * 32 + r * 16 + m16) * 40 + quad * 8];
    #pragma unroll
    for (int c = 0; c < 8; ++c)
      bf[c] = *(const s16x8*)&Bs[(c * 16 + m16) * 40 + quad * 8];
    #pragma unroll
    for (int r = 0; r < 2; ++r)
      #pragma unroll
      for (int c = 0; c < 8; ++c)
        acc[r][c] = __builtin_amdgcn_mfma_f32_16x16x32_bf16(af[r], bf[c], acc[r][c], 0, 0, 0);
    __syncthreads();
  }
  #pragma unroll
  for (int r = 0; r < 2; ++r)
    #pragma unroll
    for (int i = 0; i < 4; ++i) {
      int row = row0 + w * 32 + r * 16 + quad * 4 + i;
      #pragma unroll
      for (int c = 0; c < 8; ++c)
        C[(size_t)row * 512 + col0 + c * 16 + m16] = f2bf(acc[r][c][i]);
    }
}

// Projections: r7 block shape + XCD swizzle over a DENSE (hole-free) work space.
// s=0 tiles [0,942), s=1 [942,1416), s=2 [1416,1656). NWG=1656=8*207.
#define PROJ_NWG 1656
struct Proj3 { const unsigned short* A[3]; const unsigned short* Bt[3][3];
               unsigned short* C[3][3]; int M[3]; };
__global__ __launch_bounds__(256) void proj_mfma6(Proj3 g) {
  int orig = blockIdx.x;
  int wg = (orig & 7) * 207 + (orig >> 3);   // bijective: 1656 % 8 == 0
  int s, rem;
  if (wg < 942) { s = 0; rem = wg; }
  else if (wg < 1416) { s = 1; rem = wg - 942; }
  else { s = 2; rem = wg - 1416; }
  int by = rem / 6;
  int bx = rem - by * 6;
  int M = g.M[s];
  int row0 = by * 128;
  if (row0 >= M) return;                     // defensive (dense space: unreachable)
  int combo = bx >> 1;
  int col0 = (bx & 1) * 128;
  const unsigned short* __restrict__ A = g.A[s];
  const unsigned short* __restrict__ Bt = g.Bt[s][combo];   // 256 x 512
  unsigned short* __restrict__ C = g.C[s][combo];           // M x 256
  __shared__ unsigned short As[128 * 32];
  __shared__ unsigned short Bs[128 * 32];
  int tid = threadIdx.x, lane = tid & 63, w = tid >> 6;
  int quad = lane >> 4, m16 = lane & 15;
  int lr = lane >> 2;
  int lk = (((lane & 3) ^ (lr & 3) ^ ((lr >> 2) & 3))) * 8;
  int ar0 = row0 + w * 32 + lr;
  int ar1 = ar0 + 16;
  const unsigned short* a0p = A + (size_t)(ar0 < M ? ar0 : M - 1) * 512 + lk;
  const unsigned short* a1p = A + (size_t)(ar1 < M ? ar1 : M - 1) * 512 + lk;
  const unsigned short* b0p = Bt + (size_t)(col0 + w * 32 + lr) * 512 + lk;
  const unsigned short* b1p = b0p + (size_t)16 * 512;
  unsigned short* as0 = &As[w * 1024];
  unsigned short* as1 = &As[w * 1024 + 512];
  unsigned short* bs0 = &Bs[w * 1024];
  unsigned short* bs1 = &Bs[w * 1024 + 512];
  int wr = (w & 1) * 64, wc = (w >> 1) * 64;
  int sw = ((quad ^ (m16 & 3) ^ ((m16 >> 2) & 3))) * 8;
  f32x4 acc[4][4];
  #pragma unroll
  for (int r = 0; r < 4; ++r)
    #pragma unroll
    for (int c = 0; c < 4; ++c) acc[r][c] = (f32x4){0.f, 0.f, 0.f, 0.f};
  for (int k0 = 0; k0 < 512; k0 += 32) {
    gl16(a0p + k0, as0);
    gl16(a1p + k0, as1);
    gl16(b0p + k0, bs0);
    gl16(b1p + k0, bs1);
    __syncthreads();
    s16x8 af[4], bf[4];
    #pragma unroll
    for (int r = 0; r < 4; ++r)
      af[r] = *(const s16x8*)&As[(wr + r * 16 + m16) * 32 + sw];
    #pragma unroll
    for (int c = 0; c < 4; ++c)
      bf[c] = *(const s16x8*)&Bs[(wc + c * 16 + m16) * 32 + sw];
    #pragma unroll
    for (int r = 0; r < 4; ++r)
      #pragma unroll
      for (int c = 0; c < 4; ++c)
        acc[r][c] = __builtin_amdgcn_mfma_f32_16x16x32_bf16(af[r], bf[c], acc[r][c], 0, 0, 0);
    __syncthreads();
  }
  #pragma unroll
  for (int r = 0; r < 4; ++r)
    #pragma unroll
    for (int i = 0; i < 4; ++i) {
      int row = row0 + wr + r * 16 + quad * 4 + i;
      if (row < M) {
        #pragma unroll
        for (int c = 0; c < 4; ++c)
          C[(size_t)row * 256 + col0 + wc + c * 16 + m16] = f2bf(acc[r][c][i]);
      }
    }
}

struct Edges6 { const int* src[6]; const int* dst[6]; const float* w[6]; int nE[6]; int cbase[6]; };

// ---- CSR build: LDS-staged two-level counting sort ----
#define BSH 9
#define NB2 137            // ceil(70000 / 512)
#define CAP2 16384         // padded mean ~12.3K; huge margin + overflow path
#define NOV 65536
#define CH 1024
#define NPAY 1120000

__global__ __launch_bounds__(256) void bin1(Edges6 ep,
                                            int* __restrict__ bcur, int* __restrict__ ovcnt,
                                            unsigned long long* __restrict__ rec2,
                                            unsigned long long* __restrict__ ovbuf) {
  int rho = blockIdx.y;
  int nE = ep.nE[rho];
  int chunk = blockIdx.x * CH;
  if (chunk >= nE) return;
  int n = nE - chunk; if (n > CH) n = CH;
  const int* __restrict__ srcp = ep.src[rho];
  const int* __restrict__ dstp = ep.dst[rho];
  const float* __restrict__ wp = ep.w[rho];
  int cb = ep.cbase[rho];
  __shared__ int h[256], excl[256], lcur[256], gbase[256], rsv[256];
  __shared__ int wsum[4];
  __shared__ unsigned long long stage[CH];
  int t = threadIdx.x;
  h[t] = 0;
  gbase[t] = 0;
  __syncthreads();
  int gd[4]; unsigned pv[4];
  #pragma unroll
  for (int j = 0; j < 4; ++j) {
    int idx = t + j * 256;
    gd[j] = -1;
    if (idx < n) {
      int e = chunk + idx;
      int g = cb + dstp[e];
      if (g < 0) g = 0;
      if (g > 69999) g = 69999;       // defensive (inputs guarantee in-range)
      gd[j] = g;
      pv[j] = (((unsigned)f2bf(wp[e])) << 16) | ((unsigned)srcp[e] & 0x7fffu);
      atomicAdd(&h[g >> BSH], 1);
    }
  }
  __syncthreads();
  int hv = h[t];
  int lane = t & 63, wv = t >> 6;
  int v = hv;
  #pragma unroll
  for (int off = 1; off < 64; off <<= 1) {
    int u = __shfl_up(v, off, 64);
    if (lane >= off) v += u;
  }
  if (lane == 63) wsum[wv] = v;
  __syncthreads();
  int add = 0;
  #pragma unroll
  for (int k = 0; k < 3; ++k)
    if (k < wv) add += wsum[k];
  v += add;
  int ex = v - hv;
  excl[t] = ex;
  lcur[t] = ex;
  int rv = 0;
  if (t < NB2 && hv > 0) {
    rv = (hv + 7) & ~7;               // 64B-aligned reservation
    gbase[t] = atomicAdd(&bcur[t], rv);
  }
  rsv[t] = rv;
  __syncthreads();
  #pragma unroll
  for (int j = 0; j < 4; ++j) {
    if (gd[j] >= 0) {
      int b = gd[j] >> BSH;
      int slot = atomicAdd(&lcur[b], 1);
      if (slot >= 0 && slot < CH)
        stage[slot] = ((unsigned long long)(unsigned)gd[j] << 32) | pv[j];
    }
  }
  __syncthreads();
  for (int s = t; s < n; s += 256) {
    int lo = 0, hi = NB2 - 1;
    while (lo < hi) {
      int mid = (lo + hi + 1) >> 1;
      if (excl[mid] <= s) lo = mid; else hi = mid - 1;
    }
    int b = lo;
    int gp = gbase[b] + (s - excl[b]);
    if (gp >= 0 && gp < CAP2) rec2[(size_t)b * CAP2 + gp] = stage[s];
    else { int op = atomicAdd(ovcnt, 1); ovbuf[op & (NOV - 1)] = stage[s]; }
  }
  for (int b = t; b < NB2; b += 256) {
    int hvb = h[b], rvb = rsv[b], gb = gbase[b];
    for (int k = hvb; k < rvb; ++k) {
      int gp = gb + k;
      if (gp >= 0 && gp < CAP2) rec2[(size_t)b * CAP2 + gp] = 0xFFFFFFFFFFFFFFFFull;
    }
  }
}

__global__ __launch_bounds__(256) void cnt2(const int* __restrict__ bcur,
                                            const unsigned long long* __restrict__ rec2,
                                            const int* __restrict__ ovcnt,
                                            const unsigned long long* __restrict__ ovbuf,
                                            int* __restrict__ counts) {
  int b = blockIdx.x;
  __shared__ int c[512];
  int t = threadIdx.x;
  c[t] = 0; c[t + 256] = 0;
  __syncthreads();
  int nrec = bcur[b];
  nrec = nrec < CAP2 ? nrec : CAP2;
  const unsigned long long* rp = rec2 + (size_t)b * CAP2;
  for (int i = t; i < nrec; i += 256) {
    int gd = (int)(rp[i] >> 32);
    if (gd >= 0) atomicAdd(&c[gd & 511], 1);
  }
  int ovn = *ovcnt;
  ovn = ovn < NOV ? ovn : NOV;
  for (int i = t; i < ovn; i += 256) {
    int gd = (int)(ovbuf[i] >> 32);
    if (gd >= 0 && (gd >> BSH) == b) atomicAdd(&c[gd & 511], 1);
  }
  __syncthreads();
  int g0 = (b << BSH) + t;
  if (g0 < 70000) counts[g0] = c[t];
  int g1 = g0 + 256;
  if (g1 < 70000) counts[g1] = c[t + 256];
}

__global__ __launch_bounds__(256) void scan1(const int* __restrict__ cnt, int* __restrict__ out,
                                             int* __restrict__ part, int len) {
  __shared__ int sh[256];
  int base = blockIdx.x * 2048 + threadIdx.x * 8;
  int v[8];
  int s = 0;
  #pragma unroll
  for (int j = 0; j < 8; ++j) {
    int i = base + j;
    int x = (i < len) ? cnt[i] : 0;
    v[j] = s;
    s += x;
  }
  sh[threadIdx.x] = s;
  __syncthreads();
  for (int off = 1; off < 256; off <<= 1) {
    int t = (threadIdx.x >= off) ? sh[threadIdx.x - off] : 0;
    __syncthreads();
    sh[threadIdx.x] += t;
    __syncthreads();
  }
  int texcl = sh[threadIdx.x] - s;
  #pragma unroll
  for (int j = 0; j < 8; ++j) {
    int i = base + j;
    if (i < len) out[i] = texcl + v[j];
  }
  if (threadIdx.x == 255) part[blockIdx.x] = sh[255];
}

__global__ void scan2(int* __restrict__ part, int nb, int* __restrict__ total_out) {
  __shared__ int sh[64];
  int t = threadIdx.x;
  int v = (t < nb) ? part[t] : 0;
  sh[t] = v;
  __syncthreads();
  for (int off = 1; off < 64; off <<= 1) {
    int x = (t >= off) ? sh[t - off] : 0;
    __syncthreads();
    sh[t] += x;
    __syncthreads();
  }
  if (t < nb) part[t] = sh[t] - v;
  if (t == 63) *total_out = sh[63];
}

__global__ __launch_bounds__(256) void scan3(int* __restrict__ offs,
                                             const int* __restrict__ part, int len) {
  int i = blockIdx.x * 256 + threadIdx.x;
  if (i >= len) return;
  offs[i] += part[i >> 11];
}

__global__ __launch_bounds__(512) void fine2(const int* __restrict__ offs,
                                             const int* __restrict__ bcur,
                                             const unsigned long long* __restrict__ rec2,
                                             const int* __restrict__ ovcnt,
                                             const unsigned long long* __restrict__ ovbuf,
                                             unsigned int* __restrict__ pay) {
  int b = blockIdx.x;
  __shared__ int cur[512];
  int t = threadIdx.x;
  {
    int gd = (b << BSH) + t;
    cur[t] = (gd < 70000) ? offs[gd] : 0;
  }
  __syncthreads();
  int nrec = bcur[b];
  nrec = nrec < CAP2 ? nrec : CAP2;
  const unsigned long long* rp = rec2 + (size_t)b * CAP2;
  for (int i = t; i < nrec; i += 512) {
    unsigned long long r = rp[i];
    int gd = (int)(r >> 32);
    if (gd < 0) continue;             // sentinel pad
    int pos = atomicAdd(&cur[gd & 511], 1);
    if (pos >= 0 && pos < NPAY) pay[pos] = (unsigned)r;
  }
  int ovn = *ovcnt;
  ovn = ovn < NOV ? ovn : NOV;
  for (int i = t; i < ovn; i += 512) {
    unsigned long long r = ovbuf[i];
    int gd = (int)(r >> 32);
    if (gd >= 0 && (gd >> BSH) == b) {
      int pos = atomicAdd(&cur[gd & 511], 1);
      if (pos >= 0 && pos < NPAY) pay[pos] = (unsigned)r;
    }
  }
}

// selfdot: sdot[t][d] = dot(self[t][d], watt_t[256:512]) -- once per row.
struct Sd3 { const unsigned short* self[3]; const float* watt[3]; float* sdot[3]; };
__global__ __launch_bounds__(256) void selfdot3(Sd3 g) {
  int r = blockIdx.x * 4 + (threadIdx.x >> 6);
  int t, base;
  if (r < 20000) { t = 0; base = 0; }
  else if (r < 30000) { t = 1; base = 20000; }
  else if (r < 35000) { t = 2; base = 30000; }
  else return;
  int lane = threadIdx.x & 63;
  int d = r - base;
  ushort4 v = *(const ushort4*)(g.self[t] + (size_t)d * 256 + (lane << 2));
  float4 wb = *(const float4*)(g.watt[t] + 256 + (lane << 2));
  float s = bf2f(v.x) * wb.x + bf2f(v.y) * wb.y + bf2f(v.z) * wb.z + bf2f(v.w) * wb.w;
  #pragma unroll
  for (int off = 32; off > 0; off >>= 1) s += __shfl_down(s, off, 64);
  if (lane == 0) g.sdot[t][d] = s;
}

// all 6 relations; dense rel-major 1D grid + m204 XCD swizzle. 8 edges in
// flight per wave. FUSED raw attention score epilogue (row is in registers).
#define GAT_NWG 17500
struct Gather6 { const unsigned short* proj[6]; unsigned short* out[6];
                 const float* watt[6]; const float* sdot[6]; float* esc[6];
                 int cb[6]; int n[6]; };
__global__ __launch_bounds__(256) void gather_all(Gather6 g, const int* __restrict__ offs,
                                                  const unsigned int* __restrict__ pay) {
  int orig = blockIdx.x;
  // bijective XCD remap: q=2187, r=4  (17500 = 8*2187 + 4)
  int xcd = orig & 7, idx = orig >> 3;
  int wg = (xcd < 4 ? xcd * 2188 : 4 * 2188 + (xcd - 4) * 2187) + idx;
  int rho, base;
  if (wg < 5000) { rho = 0; base = 0; }
  else if (wg < 10000) { rho = 1; base = 5000; }
  else if (wg < 12500) { rho = 2; base = 10000; }
  else if (wg < 15000) { rho = 3; base = 12500; }
  else if (wg < 16250) { rho = 4; base = 15000; }
  else { rho = 5; base = 16250; }
  int n = g.n[rho];
  int d = (wg - base) * 4 + (threadIdx.x >> 6);
  if (d >= n) return;
  int lane = threadIdx.x & 63, half = lane >> 5, l32 = lane & 31;
  const unsigned short* __restrict__ proj = g.proj[rho];
  const int* of = offs + g.cb[rho];
  int s0 = of[d], s1 = of[d + 1];
  float acc[8] = {};
  int e = s0 + half;
  for (; e + 6 < s1; e += 8) {
    unsigned int u0 = pay[e], u1 = pay[e + 2], u2 = pay[e + 4], u3 = pay[e + 6];
    float wt0 = bf2f((unsigned short)(u0 >> 16));
    float wt1 = bf2f((unsigned short)(u1 >> 16));
    float wt2 = bf2f((unsigned short)(u2 >> 16));
    float wt3 = bf2f((unsigned short)(u3 >> 16));
    s16x8 v0 = *(const s16x8*)(proj + (size_t)(u0 & 0xffffu) * 256 + l32 * 8);
    s16x8 v1 = *(const s16x8*)(proj + (size_t)(u1 & 0xffffu) * 256 + l32 * 8);
    s16x8 v2 = *(const s16x8*)(proj + (size_t)(u2 & 0xffffu) * 256 + l32 * 8);
    s16x8 v3 = *(const s16x8*)(proj + (size_t)(u3 & 0xffffu) * 256 + l32 * 8);
    #pragma unroll
    for (int j = 0; j < 8; ++j) {
      acc[j] = fmaf(bf2f((unsigned short)v0[j]), wt0, acc[j]);
      acc[j] = fmaf(bf2f((unsigned short)v1[j]), wt1, acc[j]);
      acc[j] = fmaf(bf2f((unsigned short)v2[j]), wt2, acc[j]);
      acc[j] = fmaf(bf2f((unsigned short)v3[j]), wt3, acc[j]);
    }
  }
  for (; e < s1; e += 2) {
    unsigned int u = pay[e];
    float wt = bf2f((unsigned short)(u >> 16));
    s16x8 v = *(const s16x8*)(proj + (size_t)(u & 0xffffu) * 256 + l32 * 8);
    #pragma unroll
    for (int j = 0; j < 8; ++j) acc[j] = fmaf(bf2f((unsigned short)v[j]), wt, acc[j]);
  }
  #pragma unroll
  for (int j = 0; j < 8; ++j) acc[j] += __shfl(acc[j], lane ^ 32, 64);
  if (half == 0) {
    s16x8 o;
    #pragma unroll
    for (int j = 0; j < 8; ++j) o[j] = (short)f2bf(acc[j]);
    *(s16x8*)(g.out[rho] + (size_t)d * 256 + l32 * 8) = o;
  }
  // fused raw attention score (f32 row in registers; lane 0 stores)
  float4 wa0 = *(const float4*)(g.watt[rho] + (l32 << 3));
  float4 wa1 = *(const float4*)(g.watt[rho] + (l32 << 3) + 4);
  float sc = acc[0] * wa0.x + acc[1] * wa0.y + acc[2] * wa0.z + acc[3] * wa0.w +
             acc[4] * wa1.x + acc[5] * wa1.y + acc[6] * wa1.z + acc[7] * wa1.w;
  #pragma unroll
  for (int off = 16; off > 0; off >>= 1) sc += __shfl_xor(sc, off, 64);
  if (lane == 0) g.esc[rho][d] = sc + g.sdot[rho][d];
}

// lrelu + FAITHFUL reshape(n,2) pair-softmax over the CONCATENATED score
// vector e = [rel0 scores; rel1 scores] (length 2n): pair i = (e[2i], e[2i+1])
// -- the quirky view(-1,2) semantics the reference replicates (r13 bug: used
// (e[i], e[n+i]) cross-relation pairing -> absmax 2.1).
struct Es3 { const float* esc[3]; float* att[3]; int n[3]; };
__global__ __launch_bounds__(256) void e_soft(Es3 g) {
  int i = blockIdx.x * 256 + threadIdx.x;
  int t, base;
  if (i < 20000) { t = 0; base = 0; }
  else if (i < 30000) { t = 1; base = 20000; }
  else if (i < 35000) { t = 2; base = 30000; }
  else return;
  int d = i - base;
  float f0 = g.esc[t][2 * d], f1 = g.esc[t][2 * d + 1];
  f0 = f0 > 0.f ? f0 : 0.01f * f0;
  f1 = f1 > 0.f ? f1 : 0.01f * f1;
  float m = fmaxf(f0, f1);
  float a = expf(f0 - m), b = expf(f1 - m);
  float inv = 1.f / (a + b);
  g.att[t][2 * d] = a * inv;
  g.att[t][2 * d + 1] = b * inv;
}

// all 3 types, BM=64/BN=256, 64x64 wave tiles, pipelined staging.
struct Fin3 { const unsigned short* nb[3]; const unsigned short* self[3]; const float* att[3];
              const unsigned short* Wt[3]; const float* bias[3]; float* out[3]; int M[3]; };
__global__ __launch_bounds__(256, 3) void final_mfma3(Fin3 g) {
  int z = blockIdx.z;
  int M = g.M[z];
  int row0 = blockIdx.y * 64;
  if (row0 >= M) return;
  const unsigned short* __restrict__ nbft = g.nb[z];
  const unsigned short* __restrict__ selfb = g.self[z];
  const float* __restrict__ att = g.att[z];
  const unsigned short* __restrict__ Wt = g.Wt[z];
  __shared__ unsigned short As[64 * 40];
  __shared__ unsigned short Bs[256 * 40];
  int tid = threadIdx.x, lane = tid & 63, w = tid >> 6;
  int quad = lane >> 4, m16 = lane & 15;
  int am = tid >> 2, akk = (tid & 3) * 8;
  int gr = row0 + am;
  float a0 = 0.f, a1 = 0.f;
  if (gr < M) { a0 = att[2 * gr]; a1 = att[2 * gr + 1]; }
  f32x4 acc[4][4];
  #pragma unroll
  for (int r = 0; r < 4; ++r)
    #pragma unroll
    for (int c = 0; c < 4; ++c) acc[r][c] = (f32x4){0.f, 0.f, 0.f, 0.f};

  s16x8 pu0 = {}, pu1 = {};
  s16x8 pb[4];

  auto loadA = [&](int k0) {
    int kg = k0 + akk;
    if (gr < M) {
      if (kg < 256) {
        pu0 = *(const s16x8*)(nbft + (size_t)gr * 256 + kg);
        pu1 = *(const s16x8*)(nbft + ((size_t)M + gr) * 256 + kg);
      } else {
        pu0 = *(const s16x8*)(selfb + (size_t)gr * 256 + (kg - 256));
      }
    }
  };
  auto loadB = [&](int k0) {
    #pragma unroll
    for (int i = 0; i < 4; ++i) {
      int ch = tid + i * 256;
      int m = ch >> 2, kk = (ch & 3) * 8;
      pb[i] = *(const s16x8*)(Wt + (size_t)m * 512 + k0 + kk);
    }
  };
  auto storeLDS = [&](int k0) {
    int kg = k0 + akk;
    s16x8 v = {};
    if (gr < M) {
      if (kg < 256) {
        #pragma unroll
        for (int j = 0; j < 8; ++j)
          v[j] = (short)f2bf(fmaf(a0, bf2f((unsigned short)pu0[j]),
                                  a1 * bf2f((unsigned short)pu1[j])));
      } else {
        v = pu0;
      }
    }
    *(s16x8*)&As[am * 40 + akk] = v;
    #pragma unroll
    for (int i = 0; i < 4; ++i) {
      int ch = tid + i * 256;
      int m = ch >> 2, kk = (ch & 3) * 8;
      *(s16x8*)&Bs[m * 40 + kk] = pb[i];
    }
  };

  loadA(0); loadB(0); storeLDS(0);
  __syncthreads();
  for (int k0 = 0; k0 < 512; k0 += 32) {
    int kn = k0 + 32;
    if (kn < 512) { loadA(kn); loadB(kn); }
    s16x8 af[4], bf[4];
    #pragma unroll
    for (int r = 0; r < 4; ++r)
      af[r] = *(const s16x8*)&As[(r * 16 + m16) * 40 + quad * 8];
    #pragma unroll
    for (int c = 0; c < 4; ++c)
      bf[c] = *(const s16x8*)&Bs[(w * 64 + c * 16 + m16) * 40 + quad * 8];
    #pragma unroll
    for (int r = 0; r < 4; ++r)
      #pragma unroll
      for (int c = 0; c < 4; ++c)
        acc[r][c] = __builtin_amdgcn_mfma_f32_16x16x32_bf16(af[r], bf[c], acc[r][c], 0, 0, 0);
    __syncthreads();
    if (kn < 512) {
      storeLDS(kn);
      __syncthreads();
    }
  }
  const float* __restrict__ bias = g.bias[z];
  float* __restrict__ out = g.out[z];
  #pragma unroll
  for (int r = 0; r < 4; ++r)
    #pragma unroll
    for (int i = 0; i < 4; ++i) {
      int row = row0 + r * 16 + quad * 4 + i;
      if (row < M) {
        #pragma unroll
        for (int c = 0; c < 4; ++c) {
          int col = w * 64 + c * 16 + m16;
          out[(size_t)row * 256 + col] = acc[r][c][i] + bias[col];
        }
      }
    }
}

} // namespace

extern "C" void kernel_launch(void* const* d_in, const int* in_sizes, int n_in,
                              void* d_out, int out_size, void* d_ws, size_t ws_size,
                              hipStream_t stream) {
  (void)in_sizes; (void)n_in; (void)out_size; (void)ws_size;
  const float* x[3] = {(const float*)d_in[0], (const float*)d_in[1], (const float*)d_in[2]};

  // ---- workspace layout ----
  char* p = (char*)d_ws;
  unsigned short* projfull = (unsigned short*)p;  p += (size_t)105000 * 256 * 2;
  unsigned short* nbft = (unsigned short*)p;      p += (size_t)70000 * 256 * 2;
  unsigned short* wcatbt = (unsigned short*)p;    p += (size_t)3 * 256 * 512 * 2;
  int* offs = (int*)p;                            p += (size_t)70004 * 4;
  int* counts = (int*)p;                          p += (size_t)70000 * 4;   // cnt2 out; esc after scan1
  int* bcur = (int*)p;                            p += 160 * 4;             // zeroed
  int* ovcnt = (int*)p;                           p += 16;                  // zeroed
  int* part = (int*)p;                            p += 256;
  float* att_buf = (float*)p;                     p += (size_t)70000 * 4;
  unsigned int* csr_pay = (unsigned int*)p;       p += (size_t)1120000 * 4;
  // aliases into nbft (dead until gather_all):
  unsigned short* wshT = nbft;
  unsigned short* Wcbt = (unsigned short*)((char*)nbft + 393216);
  // record buffers alias projfull (dead until proj_mfma6 overwrites all rows):
  unsigned long long* rec2 = (unsigned long long*)projfull;            // 18 MB
  unsigned long long* ovbuf = rec2 + (size_t)NB2 * CAP2;               // 0.5 MB
  // esc (raw scores) aliases counts (dead after scan1); sdot aliases att_buf
  // [0,35000) (overwritten only by e_soft, which runs after gather).
  float* esc_buf = (float*)counts;
  // bf16 copy of x lives in d_out (dead until final_mfma3 writes real output):
  unsigned short* xb = (unsigned short*)d_out;

  const int n_of[3] = {20000, 10000, 5000};
  const int nbt[3][2] = {{1, 2}, {0, 2}, {0, 1}};
  const int ebase[3][2] = {{3, 6}, {9, 12}, {15, 18}};
  const int nE3[3] = {320000, 160000, 80000};
  const size_t out_off[3] = {0, (size_t)20000 * 256, (size_t)30000 * 256};
  const int tstart[3] = {0, 15000, 40000};
  const int selfoff[3] = {70000, 90000, 100000};
  const int nboff[3] = {0, 40000, 60000};
  const int xboff[3] = {0, 20000, 30000};
  const int sdotoff[3] = {0, 20000, 30000};

  // ---- x -> bf16 ----
  cvt_x3<<<dim3(8750), 256, 0, stream>>>(x[0], x[1], x[2], xb);

  // ---- transpose+cvt: 3 wsh, 3 wcat ----
  Tc6 tc;
  for (int t = 0; t < 3; ++t) {
    tc.src[t] = (const float*)d_in[21 + t * 7 + 3];
    tc.dst[t] = wshT + (size_t)t * 256 * 256;
    tc.R[t] = 256;
    tc.src[3 + t] = (const float*)d_in[21 + t * 7 + 5];
    tc.dst[3 + t] = wcatbt + (size_t)t * 256 * 512;
    tc.R[3 + t] = 512;
  }
  transpose_cvt<<<dim3(8, 16, 6), 256, 0, stream>>>(tc);

  // ---- combined weights via MFMA ----
  Comb9 c9;
  for (int t = 0; t < 3; ++t) {
    int wb = 21 + t * 7;
    for (int j = 0; j < 3; ++j) {
      int combo = t * 3 + j;
      c9.A[combo] = wshT + (size_t)t * 256 * 256;
      c9.B[combo] = (const float*)d_in[wb + j];
      c9.C[combo] = Wcbt + (size_t)combo * 256 * 512;
    }
  }
  combine_mfma<<<dim3(4, 2, 9), 256, 0, stream>>>(c9);

  // ---- CSR build (LDS-staged two-level counting sort) ----
  Edges6 ep;
  const int cbase[6] = {0, 20000, 40000, 50000, 60000, 65000};
  for (int t = 0; t < 3; ++t)
    for (int r = 0; r < 2; ++r) {
      int rho = t * 2 + r, eb = ebase[t][r];
      ep.src[rho] = (const int*)d_in[eb];
      ep.dst[rho] = (const int*)d_in[eb + 1];
      ep.w[rho] = (const float*)d_in[eb + 2];
      ep.nE[rho] = nE3[t];
      ep.cbase[rho] = cbase[rho];
    }
  hipMemsetAsync(bcur, 0, 160 * 4 + 16, stream);
  bin1<<<dim3(313, 6), 256, 0, stream>>>(ep, bcur, ovcnt, rec2, ovbuf);
  cnt2<<<NB2, 256, 0, stream>>>(bcur, rec2, ovcnt, ovbuf, counts);
  scan1<<<35, 256, 0, stream>>>(counts, offs, part, 70000);
  scan2<<<1, 64, 0, stream>>>(part, 35, offs + 70000);
  scan3<<<274, 256, 0, stream>>>(offs, part, 70000);
  fine2<<<NB2, 512, 0, stream>>>(offs, bcur, rec2, ovcnt, ovbuf, csr_pay);

  // ---- projections: source-keyed, dense XCD-swizzled 1D grid ----
  Proj3 pj;
  {
    int cnum[3] = {0, 0, 0};
    for (int t = 0; t < 3; ++t) {
      int m0 = n_of[nbt[t][0]];
      for (int j = 0; j < 3; ++j) {
        int s = (j == 2) ? t : nbt[t][j];
        unsigned short* dst =
            (j == 0) ? projfull + (size_t)tstart[t] * 256
          : (j == 1) ? projfull + (size_t)(tstart[t] + m0) * 256
                     : projfull + (size_t)selfoff[t] * 256;
        int c = cnum[s]++;
        pj.Bt[s][c] = Wcbt + (size_t)(t * 3 + j) * 256 * 512;
        pj.C[s][c] = dst;
      }
    }
    for (int s = 0; s < 3; ++s) {
      pj.A[s] = xb + (size_t)xboff[s] * 512;
      pj.M[s] = n_of[s];
    }
  }
  proj_mfma6<<<dim3(PROJ_NWG), 256, 0, stream>>>(pj);

  // ---- self-score dots (needs proj output) ----
  Sd3 sd;
  for (int t = 0; t < 3; ++t) {
    sd.self[t] = projfull + (size_t)selfoff[t] * 256;
    sd.watt[t] = (const float*)d_in[21 + t * 7 + 4];
    sd.sdot[t] = att_buf + sdotoff[t];
  }
  selfdot3<<<dim3(8750), 256, 0, stream>>>(sd);

  // ---- all 6 gathers + fused scores ----
  Gather6 gt;
  for (int t = 0; t < 3; ++t) {
    int m0 = n_of[nbt[t][0]];
    for (int r = 0; r < 2; ++r) {
      int rho = t * 2 + r;
      gt.proj[rho] = projfull + (size_t)(tstart[t] + (r ? m0 : 0)) * 256;
      gt.out[rho] = nbft + (size_t)(nboff[t] + r * n_of[t]) * 256;
      gt.watt[rho] = (const float*)d_in[21 + t * 7 + 4];
      gt.sdot[rho] = att_buf + sdotoff[t];
      gt.esc[rho] = esc_buf + nboff[t] + r * n_of[t];
      gt.cb[rho] = cbase[rho];
      gt.n[rho] = n_of[t];
    }
  }
  gather_all<<<dim3(GAT_NWG), 256, 0, stream>>>(gt, offs, csr_pay);

  // ---- pair softmax (overwrites att_buf; sdot dead by now) ----
  Es3 es;
  for (int t = 0; t < 3; ++t) {
    es.esc[t] = esc_buf + nboff[t];
    es.att[t] = att_buf + nboff[t];
    es.n[t] = n_of[t];
  }
  e_soft<<<dim3(137), 256, 0, stream>>>(es);

  // ---- final GEMM (3 types, BM=64, 64x64 wave tiles) ----
  Fin3 fn;
  for (int t = 0; t < 3; ++t) {
    fn.nb[t] = nbft + (size_t)nboff[t] * 256;
    fn.self[t] = projfull + (size_t)selfoff[t] * 256;
    fn.att[t] = att_buf + nboff[t];
    fn.Wt[t] = wcatbt + (size_t)t * 256 * 512;
    fn.bias[t] = (const float*)d_in[21 + t * 7 + 6];
    fn.out[t] = (float*)d_out + out_off[t];
    fn.M[t] = n_of[t];
  }
  final_mfma3<<<dim3(1, 313, 3), 256, 0, stream>>>(fn);
}